// Round 1
// baseline (503.497 us; speedup 1.0000x reference)
//
#include <hip/hip_runtime.h>
#include <math.h>

// DeformAtten2D: B=4, H=W=C=128.
// Pipeline: q = x@Wq^T  ->  offset = tanh(conv5x5_eff(q))*5  ->  bilinear sample x
//           k,v = sample@W^T (+rel_bias for v)  -> per-(b,c)-head attention over H rows
//           (feature dim = W)  ->  fused output projection (raw-reshape trick).
#define NB 4
#define IMG 16384   // 128*128

__device__ __forceinline__ float4 ld4(const float* p) {
    return *reinterpret_cast<const float4*>(p);
}

// ---------------------------------------------------------------------------
// Kernel 1: W_eff[t][tap][c] = sum_o Wc2[t,o]*Wc1[o,c,tap]; b_eff[t] = Wc2[t]·bc1
// ---------------------------------------------------------------------------
__global__ void k_weff(const float* __restrict__ Wc1, const float* __restrict__ Wc2,
                       const float* __restrict__ bc1,
                       float* __restrict__ W_eff, float* __restrict__ b_eff) {
    int idx = blockIdx.x * 256 + threadIdx.x;
    if (idx < 6400) {
        int t   = idx / 3200;
        int rem = idx - t * 3200;
        int tap = rem >> 7;
        int c   = rem & 127;
        float acc = 0.f;
        for (int o = 0; o < 128; ++o)
            acc += Wc2[t * 128 + o] * Wc1[(o * 128 + c) * 25 + tap];
        W_eff[idx] = acc;
    } else if (idx < 6402) {
        int t = idx - 6400;
        float acc = 0.f;
        for (int o = 0; o < 128; ++o) acc += Wc2[t * 128 + o] * bc1[o];
        b_eff[t] = acc;
    }
}

// ---------------------------------------------------------------------------
// Kernel 2: projection GEMM template.
//   A: (65536 pixels, 128) channel-last.  Wt: (128 out, 128 in) row-major.
//   out: channel-first (B,128,16384).  rel (opt): rel[o*128 + h] added.
// Block: 64 consecutive pixels x 128 outputs, 256 threads, 4x8 micro-tiles.
// ---------------------------------------------------------------------------
__launch_bounds__(256)
__global__ void k_proj(const float* __restrict__ A, const float* __restrict__ Wt,
                       const float* __restrict__ bias, const float* __restrict__ rel,
                       float* __restrict__ outp) {
    __shared__ float lds[8704];                 // 34.8 KB, aliased across phases
    float* Alds = lds;                          // [32][68]  = 2176 floats
    float* Blds = lds + 2176;                   // [32][132] = 4224 floats

    const int t  = threadIdx.x;
    const int pg = t & 15, og = t >> 4;         // pixel group / output group
    const int p0 = blockIdx.x * 64;             // global pixel base
    const int b  = p0 >> 14;
    const int pimg0 = p0 & (IMG - 1);
    const int hrow  = pimg0 >> 7;               // constant within tile (64 | 128)

    float acc[4][8];
#pragma unroll
    for (int i = 0; i < 4; ++i)
#pragma unroll
        for (int j = 0; j < 8; ++j) acc[i][j] = 0.f;

    for (int kc = 0; kc < 128; kc += 32) {
        // A chunk -> Alds[k][m] (transposed)
#pragma unroll
        for (int rep = 0; rep < 2; ++rep) {
            int id = rep * 256 + t;             // 0..511
            int m = id >> 3, k4 = (id & 7) * 4;
            float4 v = ld4(A + (size_t)(p0 + m) * 128 + kc + k4);
            Alds[(k4 + 0) * 68 + m] = v.x;
            Alds[(k4 + 1) * 68 + m] = v.y;
            Alds[(k4 + 2) * 68 + m] = v.z;
            Alds[(k4 + 3) * 68 + m] = v.w;
        }
        // B chunk -> Blds[k][o] (transposed)
#pragma unroll
        for (int rep = 0; rep < 4; ++rep) {
            int id = rep * 256 + t;             // 0..1023
            int o = id >> 3, k4 = (id & 7) * 4;
            float4 v = ld4(Wt + o * 128 + kc + k4);
            Blds[(k4 + 0) * 132 + o] = v.x;
            Blds[(k4 + 1) * 132 + o] = v.y;
            Blds[(k4 + 2) * 132 + o] = v.z;
            Blds[(k4 + 3) * 132 + o] = v.w;
        }
        __syncthreads();
#pragma unroll
        for (int k = 0; k < 32; ++k) {
            float4 a  = *reinterpret_cast<float4*>(&Alds[k * 68 + 4 * pg]);
            float4 b0 = *reinterpret_cast<float4*>(&Blds[k * 132 + 8 * og]);
            float4 b1 = *reinterpret_cast<float4*>(&Blds[k * 132 + 8 * og + 4]);
            float av[4] = {a.x, a.y, a.z, a.w};
            float bv[8] = {b0.x, b0.y, b0.z, b0.w, b1.x, b1.y, b1.z, b1.w};
#pragma unroll
            for (int i = 0; i < 4; ++i)
#pragma unroll
                for (int j = 0; j < 8; ++j)
                    acc[i][j] = fmaf(av[i], bv[j], acc[i][j]);
        }
        __syncthreads();
    }

    // epilogue: bias (+rel), stage [o][m] in LDS, coalesced channel-first write
    float bb[8];
#pragma unroll
    for (int j = 0; j < 8; ++j) {
        int o = 8 * og + j;
        bb[j] = bias[o] + (rel ? rel[o * 128 + hrow] : 0.f);
    }
#pragma unroll
    for (int j = 0; j < 8; ++j) {
        int o = 8 * og + j;
        float4 w0 = make_float4(acc[0][j] + bb[j], acc[1][j] + bb[j],
                                acc[2][j] + bb[j], acc[3][j] + bb[j]);
        *reinterpret_cast<float4*>(&lds[o * 68 + 4 * pg]) = w0;
    }
    __syncthreads();
    size_t outbase = (size_t)b * (128 * IMG) + pimg0;
#pragma unroll
    for (int rep = 0; rep < 8; ++rep) {
        int id = rep * 256 + t;                 // 0..2047
        int o = id >> 4, m4 = (id & 15) * 4;
        float4 v = *reinterpret_cast<float4*>(&lds[o * 68 + m4]);
        *reinterpret_cast<float4*>(outp + outbase + (size_t)o * IMG + m4) = v;
    }
}

// ---------------------------------------------------------------------------
// Kernel 3: fused 5x5 conv (2 eff. channels) -> tanh*5 offsets -> bilinear sample.
// One block per (b,h) row.  Conv: thread=(w,tch); Sample: wave per pixel, lanes=ch.
// ---------------------------------------------------------------------------
__launch_bounds__(256)
__global__ void k_offsample(const float* __restrict__ q_cf, const float* __restrict__ W_eff,
                            const float* __restrict__ b_eff, const float* __restrict__ x,
                            float* __restrict__ xs) {
    __shared__ float wl[6400];
    __shared__ float buf[5 * 132];              // 5 rows, halo 2 each side
    __shared__ float offs[256];                 // [2][128]

    const int t = threadIdx.x;
    const int bh = blockIdx.x;
    const int b = bh >> 7, h = bh & 127;

    for (int i = t; i < 6400; i += 256) wl[i] = W_eff[i];
    if (t < 5) {
        buf[t * 132 + 0] = 0.f; buf[t * 132 + 1] = 0.f;
        buf[t * 132 + 130] = 0.f; buf[t * 132 + 131] = 0.f;
    }

    const int w = t & 127, tch = t >> 7;
    float acc = 0.f;
    for (int c = 0; c < 128; ++c) {
        __syncthreads();                        // protect buf from prev-iter readers
        for (int i = t; i < 640; i += 256) {
            int r = i >> 7, ww = i & 127;
            int hr = h + r - 2;
            float v = 0.f;
            if (hr >= 0 && hr < 128)
                v = q_cf[((size_t)(b * 128 + c)) * IMG + hr * 128 + ww];
            buf[r * 132 + 2 + ww] = v;
        }
        __syncthreads();
        const float* wp = &wl[tch * 3200 + c];  // stride 128 per tap
#pragma unroll
        for (int tap = 0; tap < 25; ++tap) {
            int di = tap / 5, dj = tap % 5;
            acc = fmaf(wp[tap * 128], buf[di * 132 + w + dj], acc);
        }
    }
    offs[tch * 128 + w] = tanhf(acc + b_eff[tch]) * 5.0f;
    __syncthreads();

    const int wave = t >> 6, lane = t & 63;
    for (int px = wave; px < 128; px += 4) {
        float vx = (float)px + offs[px];        // x-offset = channel 0
        float vy = (float)h  + offs[128 + px];
        float xg = vx * (128.0f / 127.0f) - 0.5f;
        float yg = vy * (128.0f / 127.0f) - 0.5f;
        float x0f = floorf(xg), y0f = floorf(yg);
        float fx = xg - x0f, fy = yg - y0f;
        int x0 = (int)x0f, y0 = (int)y0f;
        float s0 = 0.f, s1 = 0.f;
#pragma unroll
        for (int tap = 0; tap < 4; ++tap) {
            int xi = x0 + (tap & 1), yi = y0 + (tap >> 1);
            float wgt = ((tap & 1) ? fx : 1.f - fx) * ((tap >> 1) ? fy : 1.f - fy);
            if (xi >= 0 && xi < 128 && yi >= 0 && yi < 128) {
                const float* src = x + (((size_t)(b * 128 + yi)) * 128 + xi) * 128;
                s0 = fmaf(wgt, src[lane], s0);
                s1 = fmaf(wgt, src[lane + 64], s1);
            }
        }
        float* dst = xs + (((size_t)(b * 128 + h)) * 128 + px) * 128;
        dst[lane] = s0;
        dst[lane + 64] = s1;
    }
}

// ---------------------------------------------------------------------------
// Kernel 4: per-head attention + fused output projection.
//   head = b*128+c; q/k/v planes contiguous 64KB.  S kept transposed S_T[j][i].
//   Y = softmax(q k^T * s) v @ Wo^T + bo  written straight to d_out (reshape trick).
// ---------------------------------------------------------------------------
__launch_bounds__(256)
__global__ void k_attn(const float* __restrict__ q_cf, const float* __restrict__ k_cf,
                       const float* __restrict__ v_cf, const float* __restrict__ Wo,
                       const float* __restrict__ bo, float* __restrict__ outp) {
    __shared__ float S[128 * 132];              // S_T[j][i], later O_T[d][i]
    __shared__ float cb0[32 * 132];
    __shared__ float cb1[32 * 132];

    const int t = threadIdx.x;
    const int ti = t & 15, tj = t >> 4;
    const size_t hb = (size_t)blockIdx.x * IMG;
    const float* qp = q_cf + hb;
    const float* kp = k_cf + hb;
    const float* vp = v_cf + hb;
    float acc[8][8];

    // ---- Phase 1: S_T[j][i] = scale * sum_d q[i,d]*k[j,d] ----
#pragma unroll
    for (int i = 0; i < 8; ++i)
#pragma unroll
        for (int j = 0; j < 8; ++j) acc[i][j] = 0.f;

    for (int d0 = 0; d0 < 128; d0 += 32) {
#pragma unroll
        for (int rep = 0; rep < 4; ++rep) {
            int id = rep * 256 + t;
            int i = id >> 3, d4 = (id & 7) * 4;
            float4 qv = ld4(qp + i * 128 + d0 + d4);
            float4 kv = ld4(kp + i * 128 + d0 + d4);
            cb0[(d4 + 0) * 132 + i] = qv.x; cb0[(d4 + 1) * 132 + i] = qv.y;
            cb0[(d4 + 2) * 132 + i] = qv.z; cb0[(d4 + 3) * 132 + i] = qv.w;
            cb1[(d4 + 0) * 132 + i] = kv.x; cb1[(d4 + 1) * 132 + i] = kv.y;
            cb1[(d4 + 2) * 132 + i] = kv.z; cb1[(d4 + 3) * 132 + i] = kv.w;
        }
        __syncthreads();
#pragma unroll
        for (int dd = 0; dd < 32; ++dd) {
            float4 a0 = *reinterpret_cast<float4*>(&cb0[dd * 132 + 8 * ti]);
            float4 a1 = *reinterpret_cast<float4*>(&cb0[dd * 132 + 8 * ti + 4]);
            float4 b0 = *reinterpret_cast<float4*>(&cb1[dd * 132 + 8 * tj]);
            float4 b1 = *reinterpret_cast<float4*>(&cb1[dd * 132 + 8 * tj + 4]);
            float av[8] = {a0.x, a0.y, a0.z, a0.w, a1.x, a1.y, a1.z, a1.w};
            float bv[8] = {b0.x, b0.y, b0.z, b0.w, b1.x, b1.y, b1.z, b1.w};
#pragma unroll
            for (int i = 0; i < 8; ++i)
#pragma unroll
                for (int j = 0; j < 8; ++j)
                    acc[i][j] = fmaf(av[i], bv[j], acc[i][j]);
        }
        __syncthreads();
    }
    const float scale = 0.08838834764831845f;
#pragma unroll
    for (int j = 0; j < 8; ++j) {
        *reinterpret_cast<float4*>(&S[(8 * tj + j) * 132 + 8 * ti]) =
            make_float4(acc[0][j] * scale, acc[1][j] * scale, acc[2][j] * scale, acc[3][j] * scale);
        *reinterpret_cast<float4*>(&S[(8 * tj + j) * 132 + 8 * ti + 4]) =
            make_float4(acc[4][j] * scale, acc[5][j] * scale, acc[6][j] * scale, acc[7][j] * scale);
    }
    __syncthreads();

    // ---- softmax over j for each column i ----
    if (t < 128) {
        float m = -1e30f;
        for (int j = 0; j < 128; ++j) m = fmaxf(m, S[j * 132 + t]);
        float ssum = 0.f;
        for (int j = 0; j < 128; ++j) {
            float e = __expf(S[j * 132 + t] - m);
            S[j * 132 + t] = e;
            ssum += e;
        }
        float inv = 1.0f / ssum;
        for (int j = 0; j < 128; ++j) S[j * 132 + t] *= inv;
    }
    __syncthreads();

    // ---- Phase 2: O[i,d] = sum_j P[i,j]*v[j,d] ----
#pragma unroll
    for (int i = 0; i < 8; ++i)
#pragma unroll
        for (int j = 0; j < 8; ++j) acc[i][j] = 0.f;

    for (int j0 = 0; j0 < 128; j0 += 32) {
#pragma unroll
        for (int rep = 0; rep < 4; ++rep) {
            int id = rep * 256 + t;
            int jl = id >> 5, d4 = (id & 31) * 4;
            *reinterpret_cast<float4*>(&cb1[jl * 132 + d4]) =
                ld4(vp + (size_t)(j0 + jl) * 128 + d4);
        }
        __syncthreads();
#pragma unroll
        for (int jl = 0; jl < 32; ++jl) {
            float4 a0 = *reinterpret_cast<float4*>(&S[(j0 + jl) * 132 + 8 * ti]);
            float4 a1 = *reinterpret_cast<float4*>(&S[(j0 + jl) * 132 + 8 * ti + 4]);
            float4 b0 = *reinterpret_cast<float4*>(&cb1[jl * 132 + 8 * tj]);
            float4 b1 = *reinterpret_cast<float4*>(&cb1[jl * 132 + 8 * tj + 4]);
            float av[8] = {a0.x, a0.y, a0.z, a0.w, a1.x, a1.y, a1.z, a1.w};
            float bv[8] = {b0.x, b0.y, b0.z, b0.w, b1.x, b1.y, b1.z, b1.w};
#pragma unroll
            for (int i = 0; i < 8; ++i)
#pragma unroll
                for (int j = 0; j < 8; ++j)
                    acc[i][j] = fmaf(av[i], bv[j], acc[i][j]);
        }
        __syncthreads();
    }
    // O_T[d][i] into S (d = 8*tj+jj)
#pragma unroll
    for (int j = 0; j < 8; ++j) {
        *reinterpret_cast<float4*>(&S[(8 * tj + j) * 132 + 8 * ti]) =
            make_float4(acc[0][j], acc[1][j], acc[2][j], acc[3][j]);
        *reinterpret_cast<float4*>(&S[(8 * tj + j) * 132 + 8 * ti + 4]) =
            make_float4(acc[4][j], acc[5][j], acc[6][j], acc[7][j]);
    }
    __syncthreads();

    // ---- Phase 3: Y[i,o] = sum_d O[i,d]*Wo[o,d] + bo[o] ----
#pragma unroll
    for (int i = 0; i < 8; ++i)
#pragma unroll
        for (int j = 0; j < 8; ++j) acc[i][j] = 0.f;

    for (int d0 = 0; d0 < 128; d0 += 32) {
#pragma unroll
        for (int rep = 0; rep < 4; ++rep) {
            int id = rep * 256 + t;
            int o = id >> 3, d4 = (id & 7) * 4;
            float4 wv = ld4(Wo + o * 128 + d0 + d4);
            cb0[(d4 + 0) * 132 + o] = wv.x; cb0[(d4 + 1) * 132 + o] = wv.y;
            cb0[(d4 + 2) * 132 + o] = wv.z; cb0[(d4 + 3) * 132 + o] = wv.w;
        }
        __syncthreads();
#pragma unroll
        for (int dl = 0; dl < 32; ++dl) {
            float4 a0 = *reinterpret_cast<float4*>(&S[(d0 + dl) * 132 + 8 * ti]);
            float4 a1 = *reinterpret_cast<float4*>(&S[(d0 + dl) * 132 + 8 * ti + 4]);
            float4 b0 = *reinterpret_cast<float4*>(&cb0[dl * 132 + 8 * tj]);
            float4 b1 = *reinterpret_cast<float4*>(&cb0[dl * 132 + 8 * tj + 4]);
            float av[8] = {a0.x, a0.y, a0.z, a0.w, a1.x, a1.y, a1.z, a1.w};
            float bv[8] = {b0.x, b0.y, b0.z, b0.w, b1.x, b1.y, b1.z, b1.w};
#pragma unroll
            for (int i = 0; i < 8; ++i)
#pragma unroll
                for (int j = 0; j < 8; ++j)
                    acc[i][j] = fmaf(av[i], bv[j], acc[i][j]);
        }
        __syncthreads();
    }
    float bb[8];
#pragma unroll
    for (int j = 0; j < 8; ++j) bb[j] = bo[8 * tj + j];
#pragma unroll
    for (int i = 0; i < 8; ++i) {
        int row = 8 * ti + i;
        *reinterpret_cast<float4*>(outp + hb + (size_t)row * 128 + 8 * tj) =
            make_float4(acc[i][0] + bb[0], acc[i][1] + bb[1], acc[i][2] + bb[2], acc[i][3] + bb[3]);
        *reinterpret_cast<float4*>(outp + hb + (size_t)row * 128 + 8 * tj + 4) =
            make_float4(acc[i][4] + bb[4], acc[i][5] + bb[5], acc[i][6] + bb[6], acc[i][7] + bb[7]);
    }
}

// ---------------------------------------------------------------------------
extern "C" void kernel_launch(void* const* d_in, const int* in_sizes, int n_in,
                              void* d_out, int out_size, void* d_ws, size_t ws_size,
                              hipStream_t stream) {
    const float* x   = (const float*)d_in[0];
    // d_in[1] = cycle_index (dead path)
    const float* Wq  = (const float*)d_in[2];
    const float* bq  = (const float*)d_in[3];
    const float* Wk  = (const float*)d_in[4];
    const float* bk  = (const float*)d_in[5];
    const float* Wv  = (const float*)d_in[6];
    const float* bv  = (const float*)d_in[7];
    const float* Wo  = (const float*)d_in[8];
    const float* bo  = (const float*)d_in[9];
    const float* Wc1 = (const float*)d_in[10];
    const float* bc1 = (const float*)d_in[11];
    const float* Wc2 = (const float*)d_in[12];
    const float* rel = (const float*)d_in[13];

    float* ws = (float*)d_ws;
    float* q_cf  = ws;                 // 8388608 floats, (B,C,H,W)
    float* xs_cl = ws + 8388608;       // 8388608, (B,H,W,C)
    float* k_cf  = ws + 16777216;      // 8388608
    float* v_cf  = ws + 25165824;      // 8388608
    float* W_eff = ws + 33554432;      // 6400
    float* b_eff = ws + 33560832;      // 2
    float* outp  = (float*)d_out;

    hipLaunchKernelGGL(k_weff, dim3(26), dim3(256), 0, stream, Wc1, Wc2, bc1, W_eff, b_eff);
    hipLaunchKernelGGL(k_proj, dim3(1024), dim3(256), 0, stream, x, Wq, bq, (const float*)nullptr, q_cf);
    hipLaunchKernelGGL(k_offsample, dim3(512), dim3(256), 0, stream, q_cf, W_eff, b_eff, x, xs_cl);
    hipLaunchKernelGGL(k_proj, dim3(1024), dim3(256), 0, stream, xs_cl, Wk, bk, (const float*)nullptr, k_cf);
    hipLaunchKernelGGL(k_proj, dim3(1024), dim3(256), 0, stream, xs_cl, Wv, bv, rel, v_cf);
    hipLaunchKernelGGL(k_attn, dim3(512), dim3(256), 0, stream, q_cf, k_cf, v_cf, Wo, bo, outp);
}

// Round 2
// 414.096 us; speedup vs baseline: 1.2159x; 1.2159x over previous
//
#include <hip/hip_runtime.h>
#include <math.h>

// DeformAtten2D: B=4, H=W=C=128.
// q = x@Wq^T ; offset = tanh(conv5x5_eff(q))*5 ; bilinear sample x ;
// k,v = sample@W^T (+rel_bias for v) ; per-(b,c)-head attention over H rows ;
// fused output projection (raw-reshape trick).
//
// R2: offset path restructured. conv(chan-reduce) is linear and commutes with
// Wq, so P[(t,tap),pix] = W2 @ x + cst (50x128 GEMM on x), then the 5x5 conv
// is 25 shifted row-adds of P planes. Kills the 128-iteration serialized
// channel loop (193us, 130MB of q_cf traffic) from R1.
#define NB 4
#define IMG 16384   // 128*128

__device__ __forceinline__ float4 ld4(const float* p) {
    return *reinterpret_cast<const float4*>(p);
}

// ---------------------------------------------------------------------------
// Kernel 1a: W_eff[o50][c] = sum_o Wc2[t,o]*Wc1[o,c,tap]  (o50 = t*25+tap)
//            b_eff[t] = Wc2[t]·bc1
// ---------------------------------------------------------------------------
__global__ void k_weff(const float* __restrict__ Wc1, const float* __restrict__ Wc2,
                       const float* __restrict__ bc1,
                       float* __restrict__ W_eff, float* __restrict__ b_eff) {
    int idx = blockIdx.x * 256 + threadIdx.x;
    if (idx < 6400) {
        int t   = idx / 3200;
        int rem = idx - t * 3200;
        int tap = rem >> 7;
        int c   = rem & 127;
        float acc = 0.f;
        for (int o = 0; o < 128; ++o)
            acc += Wc2[t * 128 + o] * Wc1[(o * 128 + c) * 25 + tap];
        W_eff[idx] = acc;
    } else if (idx < 6402) {
        int t = idx - 6400;
        float acc = 0.f;
        for (int o = 0; o < 128; ++o) acc += Wc2[t * 128 + o] * bc1[o];
        b_eff[t] = acc;
    }
}

// ---------------------------------------------------------------------------
// Kernel 1b: fold Wq/bq:  W2[o50][i] = sum_c W_eff[o50][c]*Wq[c][i]
//            cst[o50] = W_eff[o50]·bq
// ---------------------------------------------------------------------------
__global__ void k_weff2(const float* __restrict__ W_eff, const float* __restrict__ Wq,
                        const float* __restrict__ bq,
                        float* __restrict__ W2, float* __restrict__ cst) {
    int idx = blockIdx.x * 256 + threadIdx.x;
    if (idx < 6400) {
        int o = idx >> 7, i = idx & 127;
        float acc = 0.f;
        for (int c = 0; c < 128; ++c)
            acc += W_eff[o * 128 + c] * Wq[c * 128 + i];
        W2[idx] = acc;
    } else if (idx < 6450) {
        int o = idx - 6400;
        float acc = 0.f;
        for (int c = 0; c < 128; ++c) acc += W_eff[o * 128 + c] * bq[c];
        cst[o] = acc;
    }
}

// ---------------------------------------------------------------------------
// Kernel 2: projection GEMM template (q/k/v).
//   A: (65536 pixels, 128) channel-last.  Wt: (128 out, 128 in) row-major.
//   out: channel-first (B,128,16384).  rel (opt): rel[o*128 + h] added.
// ---------------------------------------------------------------------------
__launch_bounds__(256)
__global__ void k_proj(const float* __restrict__ A, const float* __restrict__ Wt,
                       const float* __restrict__ bias, const float* __restrict__ rel,
                       float* __restrict__ outp) {
    __shared__ float lds[8704];
    float* Alds = lds;                          // [32][68]
    float* Blds = lds + 2176;                   // [32][132]

    const int t  = threadIdx.x;
    const int pg = t & 15, og = t >> 4;
    const int p0 = blockIdx.x * 64;
    const int b  = p0 >> 14;
    const int pimg0 = p0 & (IMG - 1);
    const int hrow  = pimg0 >> 7;

    float acc[4][8];
#pragma unroll
    for (int i = 0; i < 4; ++i)
#pragma unroll
        for (int j = 0; j < 8; ++j) acc[i][j] = 0.f;

    for (int kc = 0; kc < 128; kc += 32) {
#pragma unroll
        for (int rep = 0; rep < 2; ++rep) {
            int id = rep * 256 + t;
            int m = id >> 3, k4 = (id & 7) * 4;
            float4 v = ld4(A + (size_t)(p0 + m) * 128 + kc + k4);
            Alds[(k4 + 0) * 68 + m] = v.x;
            Alds[(k4 + 1) * 68 + m] = v.y;
            Alds[(k4 + 2) * 68 + m] = v.z;
            Alds[(k4 + 3) * 68 + m] = v.w;
        }
#pragma unroll
        for (int rep = 0; rep < 4; ++rep) {
            int id = rep * 256 + t;
            int o = id >> 3, k4 = (id & 7) * 4;
            float4 v = ld4(Wt + o * 128 + kc + k4);
            Blds[(k4 + 0) * 132 + o] = v.x;
            Blds[(k4 + 1) * 132 + o] = v.y;
            Blds[(k4 + 2) * 132 + o] = v.z;
            Blds[(k4 + 3) * 132 + o] = v.w;
        }
        __syncthreads();
#pragma unroll
        for (int k = 0; k < 32; ++k) {
            float4 a  = *reinterpret_cast<float4*>(&Alds[k * 68 + 4 * pg]);
            float4 b0 = *reinterpret_cast<float4*>(&Blds[k * 132 + 8 * og]);
            float4 b1 = *reinterpret_cast<float4*>(&Blds[k * 132 + 8 * og + 4]);
            float av[4] = {a.x, a.y, a.z, a.w};
            float bv[8] = {b0.x, b0.y, b0.z, b0.w, b1.x, b1.y, b1.z, b1.w};
#pragma unroll
            for (int i = 0; i < 4; ++i)
#pragma unroll
                for (int j = 0; j < 8; ++j)
                    acc[i][j] = fmaf(av[i], bv[j], acc[i][j]);
        }
        __syncthreads();
    }

    float bb[8];
#pragma unroll
    for (int j = 0; j < 8; ++j) {
        int o = 8 * og + j;
        bb[j] = bias[o] + (rel ? rel[o * 128 + hrow] : 0.f);
    }
#pragma unroll
    for (int j = 0; j < 8; ++j) {
        int o = 8 * og + j;
        float4 w0 = make_float4(acc[0][j] + bb[j], acc[1][j] + bb[j],
                                acc[2][j] + bb[j], acc[3][j] + bb[j]);
        *reinterpret_cast<float4*>(&lds[o * 68 + 4 * pg]) = w0;
    }
    __syncthreads();
    size_t outbase = (size_t)b * (128 * IMG) + pimg0;
#pragma unroll
    for (int rep = 0; rep < 8; ++rep) {
        int id = rep * 256 + t;
        int o = id >> 4, m4 = (id & 15) * 4;
        float4 v = *reinterpret_cast<float4*>(&lds[o * 68 + m4]);
        *reinterpret_cast<float4*>(outp + outbase + (size_t)o * IMG + m4) = v;
    }
}

// ---------------------------------------------------------------------------
// Kernel 3a: P[b][o50][pix] = W2[o50]·x[pix] + cst[o50]   (64px x 64out tiles)
// ---------------------------------------------------------------------------
__launch_bounds__(256)
__global__ void k_off(const float* __restrict__ x, const float* __restrict__ W2,
                      const float* __restrict__ cst, float* __restrict__ P) {
    __shared__ float Wlds[128 * 68];            // [k][o] padded, later [o][px]
    __shared__ float Alds[32 * 68];             // [k][px]
    const int t = threadIdx.x;
    const int pg = t & 15, og = t >> 4;
    const int p0 = blockIdx.x * 64;
    const int b = p0 >> 14, pix0 = p0 & (IMG - 1);

    for (int id = t; id < 128 * 64; id += 256) {
        int k = id >> 6, o = id & 63;
        Wlds[k * 68 + o] = (o < 50) ? W2[o * 128 + k] : 0.f;
    }

    float acc[4][4];
#pragma unroll
    for (int i = 0; i < 4; ++i)
#pragma unroll
        for (int j = 0; j < 4; ++j) acc[i][j] = 0.f;

    for (int kc = 0; kc < 128; kc += 32) {
        __syncthreads();                        // Wlds ready (1st) / Alds readers done
#pragma unroll
        for (int rep = 0; rep < 2; ++rep) {
            int id = rep * 256 + t;
            int m = id >> 3, k4 = (id & 7) * 4;
            float4 v = ld4(x + (size_t)(p0 + m) * 128 + kc + k4);
            Alds[(k4 + 0) * 68 + m] = v.x;
            Alds[(k4 + 1) * 68 + m] = v.y;
            Alds[(k4 + 2) * 68 + m] = v.z;
            Alds[(k4 + 3) * 68 + m] = v.w;
        }
        __syncthreads();
#pragma unroll
        for (int k = 0; k < 32; ++k) {
            float4 a = *reinterpret_cast<float4*>(&Alds[k * 68 + 4 * pg]);
            float4 w = *reinterpret_cast<float4*>(&Wlds[(kc + k) * 68 + 4 * og]);
            float av[4] = {a.x, a.y, a.z, a.w};
            float wv[4] = {w.x, w.y, w.z, w.w};
#pragma unroll
            for (int i = 0; i < 4; ++i)
#pragma unroll
                for (int j = 0; j < 4; ++j)
                    acc[i][j] = fmaf(av[i], wv[j], acc[i][j]);
        }
    }
    __syncthreads();
#pragma unroll
    for (int j = 0; j < 4; ++j) {
        int o = 4 * og + j;
        float c = (o < 50) ? cst[o] : 0.f;
        *reinterpret_cast<float4*>(&Wlds[o * 68 + 4 * pg]) =
            make_float4(acc[0][j] + c, acc[1][j] + c, acc[2][j] + c, acc[3][j] + c);
    }
    __syncthreads();
    for (int id = t; id < 50 * 16; id += 256) {
        int o = id >> 4, px4 = (id & 15) * 4;
        float4 v = *reinterpret_cast<float4*>(&Wlds[o * 68 + px4]);
        *reinterpret_cast<float4*>(P + ((size_t)(b * 50 + o)) * IMG + pix0 + px4) = v;
    }
}

// ---------------------------------------------------------------------------
// Kernel 3b: per (b,h) row: 25-tap shift-add of P planes -> tanh*5 -> bilinear.
// ---------------------------------------------------------------------------
__launch_bounds__(256)
__global__ void k_sample(const float* __restrict__ P, const float* __restrict__ b_eff,
                         const float* __restrict__ x, float* __restrict__ xs) {
    __shared__ float rows[50 * 132];
    __shared__ float offs[256];
    const int t = threadIdx.x;
    const int bh = blockIdx.x;
    const int b = bh >> 7, h = bh & 127;

    // each tap (di,dj) needs P-plane row h+di-2 (zero if out of range)
    for (int id = t; id < 50 * 32; id += 256) {
        int o = id >> 5, q4 = (id & 31) * 4;
        int di = (o % 25) / 5;
        int r = h + di - 2;
        float4 v = make_float4(0.f, 0.f, 0.f, 0.f);
        if (r >= 0 && r < 128)
            v = ld4(P + ((size_t)(b * 50 + o)) * IMG + r * 128 + q4);
        *reinterpret_cast<float4*>(&rows[o * 132 + q4]) = v;
    }
    __syncthreads();
    {
        int w = t & 127, tc = t >> 7;
        float acc = 0.f;
#pragma unroll
        for (int di = 0; di < 5; ++di)
#pragma unroll
            for (int dj = 0; dj < 5; ++dj) {
                int wj = w + dj - 2;
                if (wj >= 0 && wj < 128)
                    acc += rows[(tc * 25 + di * 5 + dj) * 132 + wj];
            }
        offs[tc * 128 + w] = tanhf(acc + b_eff[tc]) * 5.0f;
    }
    __syncthreads();

    const int wave = t >> 6, lane = t & 63;
    for (int px = wave; px < 128; px += 4) {
        float vx = (float)px + offs[px];        // channel 0 -> x coord
        float vy = (float)h  + offs[128 + px];
        float xg = vx * (128.0f / 127.0f) - 0.5f;
        float yg = vy * (128.0f / 127.0f) - 0.5f;
        float x0f = floorf(xg), y0f = floorf(yg);
        float fx = xg - x0f, fy = yg - y0f;
        int x0 = (int)x0f, y0 = (int)y0f;
        float s0 = 0.f, s1 = 0.f;
#pragma unroll
        for (int tap = 0; tap < 4; ++tap) {
            int xi = x0 + (tap & 1), yi = y0 + (tap >> 1);
            float wgt = ((tap & 1) ? fx : 1.f - fx) * ((tap >> 1) ? fy : 1.f - fy);
            if (xi >= 0 && xi < 128 && yi >= 0 && yi < 128) {
                const float* src = x + (((size_t)(b * 128 + yi)) * 128 + xi) * 128;
                s0 = fmaf(wgt, src[lane], s0);
                s1 = fmaf(wgt, src[lane + 64], s1);
            }
        }
        float* dst = xs + (((size_t)(b * 128 + h)) * 128 + px) * 128;
        dst[lane] = s0;
        dst[lane + 64] = s1;
    }
}

// ---------------------------------------------------------------------------
// Kernel 4: per-head attention + fused output projection.
// ---------------------------------------------------------------------------
__launch_bounds__(256)
__global__ void k_attn(const float* __restrict__ q_cf, const float* __restrict__ k_cf,
                       const float* __restrict__ v_cf, const float* __restrict__ Wo,
                       const float* __restrict__ bo, float* __restrict__ outp) {
    __shared__ float S[128 * 132];
    __shared__ float cb0[32 * 132];
    __shared__ float cb1[32 * 132];

    const int t = threadIdx.x;
    const int ti = t & 15, tj = t >> 4;
    const size_t hb = (size_t)blockIdx.x * IMG;
    const float* qp = q_cf + hb;
    const float* kp = k_cf + hb;
    const float* vp = v_cf + hb;
    float acc[8][8];

#pragma unroll
    for (int i = 0; i < 8; ++i)
#pragma unroll
        for (int j = 0; j < 8; ++j) acc[i][j] = 0.f;

    for (int d0 = 0; d0 < 128; d0 += 32) {
#pragma unroll
        for (int rep = 0; rep < 4; ++rep) {
            int id = rep * 256 + t;
            int i = id >> 3, d4 = (id & 7) * 4;
            float4 qv = ld4(qp + i * 128 + d0 + d4);
            float4 kv = ld4(kp + i * 128 + d0 + d4);
            cb0[(d4 + 0) * 132 + i] = qv.x; cb0[(d4 + 1) * 132 + i] = qv.y;
            cb0[(d4 + 2) * 132 + i] = qv.z; cb0[(d4 + 3) * 132 + i] = qv.w;
            cb1[(d4 + 0) * 132 + i] = kv.x; cb1[(d4 + 1) * 132 + i] = kv.y;
            cb1[(d4 + 2) * 132 + i] = kv.z; cb1[(d4 + 3) * 132 + i] = kv.w;
        }
        __syncthreads();
#pragma unroll
        for (int dd = 0; dd < 32; ++dd) {
            float4 a0 = *reinterpret_cast<float4*>(&cb0[dd * 132 + 8 * ti]);
            float4 a1 = *reinterpret_cast<float4*>(&cb0[dd * 132 + 8 * ti + 4]);
            float4 b0 = *reinterpret_cast<float4*>(&cb1[dd * 132 + 8 * tj]);
            float4 b1 = *reinterpret_cast<float4*>(&cb1[dd * 132 + 8 * tj + 4]);
            float av[8] = {a0.x, a0.y, a0.z, a0.w, a1.x, a1.y, a1.z, a1.w};
            float bv[8] = {b0.x, b0.y, b0.z, b0.w, b1.x, b1.y, b1.z, b1.w};
#pragma unroll
            for (int i = 0; i < 8; ++i)
#pragma unroll
                for (int j = 0; j < 8; ++j)
                    acc[i][j] = fmaf(av[i], bv[j], acc[i][j]);
        }
        __syncthreads();
    }
    const float scale = 0.08838834764831845f;
#pragma unroll
    for (int j = 0; j < 8; ++j) {
        *reinterpret_cast<float4*>(&S[(8 * tj + j) * 132 + 8 * ti]) =
            make_float4(acc[0][j] * scale, acc[1][j] * scale, acc[2][j] * scale, acc[3][j] * scale);
        *reinterpret_cast<float4*>(&S[(8 * tj + j) * 132 + 8 * ti + 4]) =
            make_float4(acc[4][j] * scale, acc[5][j] * scale, acc[6][j] * scale, acc[7][j] * scale);
    }
    __syncthreads();

    if (t < 128) {
        float m = -1e30f;
        for (int j = 0; j < 128; ++j) m = fmaxf(m, S[j * 132 + t]);
        float ssum = 0.f;
        for (int j = 0; j < 128; ++j) {
            float e = __expf(S[j * 132 + t] - m);
            S[j * 132 + t] = e;
            ssum += e;
        }
        float inv = 1.0f / ssum;
        for (int j = 0; j < 128; ++j) S[j * 132 + t] *= inv;
    }
    __syncthreads();

#pragma unroll
    for (int i = 0; i < 8; ++i)
#pragma unroll
        for (int j = 0; j < 8; ++j) acc[i][j] = 0.f;

    for (int j0 = 0; j0 < 128; j0 += 32) {
#pragma unroll
        for (int rep = 0; rep < 4; ++rep) {
            int id = rep * 256 + t;
            int jl = id >> 5, d4 = (id & 31) * 4;
            *reinterpret_cast<float4*>(&cb1[jl * 132 + d4]) =
                ld4(vp + (size_t)(j0 + jl) * 128 + d4);
        }
        __syncthreads();
#pragma unroll
        for (int jl = 0; jl < 32; ++jl) {
            float4 a0 = *reinterpret_cast<float4*>(&S[(j0 + jl) * 132 + 8 * ti]);
            float4 a1 = *reinterpret_cast<float4*>(&S[(j0 + jl) * 132 + 8 * ti + 4]);
            float4 b0 = *reinterpret_cast<float4*>(&cb1[jl * 132 + 8 * tj]);
            float4 b1 = *reinterpret_cast<float4*>(&cb1[jl * 132 + 8 * tj + 4]);
            float av[8] = {a0.x, a0.y, a0.z, a0.w, a1.x, a1.y, a1.z, a1.w};
            float bv[8] = {b0.x, b0.y, b0.z, b0.w, b1.x, b1.y, b1.z, b1.w};
#pragma unroll
            for (int i = 0; i < 8; ++i)
#pragma unroll
                for (int j = 0; j < 8; ++j)
                    acc[i][j] = fmaf(av[i], bv[j], acc[i][j]);
        }
        __syncthreads();
    }
#pragma unroll
    for (int j = 0; j < 8; ++j) {
        *reinterpret_cast<float4*>(&S[(8 * tj + j) * 132 + 8 * ti]) =
            make_float4(acc[0][j], acc[1][j], acc[2][j], acc[3][j]);
        *reinterpret_cast<float4*>(&S[(8 * tj + j) * 132 + 8 * ti + 4]) =
            make_float4(acc[4][j], acc[5][j], acc[6][j], acc[7][j]);
    }
    __syncthreads();

#pragma unroll
    for (int i = 0; i < 8; ++i)
#pragma unroll
        for (int j = 0; j < 8; ++j) acc[i][j] = 0.f;

    for (int d0 = 0; d0 < 128; d0 += 32) {
#pragma unroll
        for (int rep = 0; rep < 4; ++rep) {
            int id = rep * 256 + t;
            int o = id >> 3, d4 = (id & 7) * 4;
            float4 wv = ld4(Wo + o * 128 + d0 + d4);
            cb0[(d4 + 0) * 132 + o] = wv.x; cb0[(d4 + 1) * 132 + o] = wv.y;
            cb0[(d4 + 2) * 132 + o] = wv.z; cb0[(d4 + 3) * 132 + o] = wv.w;
        }
        __syncthreads();
#pragma unroll
        for (int dl = 0; dl < 32; ++dl) {
            float4 a0 = *reinterpret_cast<float4*>(&S[(d0 + dl) * 132 + 8 * ti]);
            float4 a1 = *reinterpret_cast<float4*>(&S[(d0 + dl) * 132 + 8 * ti + 4]);
            float4 b0 = *reinterpret_cast<float4*>(&cb0[dl * 132 + 8 * tj]);
            float4 b1 = *reinterpret_cast<float4*>(&cb0[dl * 132 + 8 * tj + 4]);
            float av[8] = {a0.x, a0.y, a0.z, a0.w, a1.x, a1.y, a1.z, a1.w};
            float bv[8] = {b0.x, b0.y, b0.z, b0.w, b1.x, b1.y, b1.z, b1.w};
#pragma unroll
            for (int i = 0; i < 8; ++i)
#pragma unroll
                for (int j = 0; j < 8; ++j)
                    acc[i][j] = fmaf(av[i], bv[j], acc[i][j]);
        }
        __syncthreads();
    }
    float bb[8];
#pragma unroll
    for (int j = 0; j < 8; ++j) bb[j] = bo[8 * tj + j];
#pragma unroll
    for (int i = 0; i < 8; ++i) {
        int row = 8 * ti + i;
        *reinterpret_cast<float4*>(outp + hb + (size_t)row * 128 + 8 * tj) =
            make_float4(acc[i][0] + bb[0], acc[i][1] + bb[1], acc[i][2] + bb[2], acc[i][3] + bb[3]);
        *reinterpret_cast<float4*>(outp + hb + (size_t)row * 128 + 8 * tj + 4) =
            make_float4(acc[i][4] + bb[4], acc[i][5] + bb[5], acc[i][6] + bb[6], acc[i][7] + bb[7]);
    }
}

// ---------------------------------------------------------------------------
extern "C" void kernel_launch(void* const* d_in, const int* in_sizes, int n_in,
                              void* d_out, int out_size, void* d_ws, size_t ws_size,
                              hipStream_t stream) {
    const float* x   = (const float*)d_in[0];
    // d_in[1] = cycle_index (dead path)
    const float* Wq  = (const float*)d_in[2];
    const float* bq  = (const float*)d_in[3];
    const float* Wk  = (const float*)d_in[4];
    const float* bk  = (const float*)d_in[5];
    const float* Wv  = (const float*)d_in[6];
    const float* bv  = (const float*)d_in[7];
    const float* Wo  = (const float*)d_in[8];
    const float* bo  = (const float*)d_in[9];
    const float* Wc1 = (const float*)d_in[10];
    const float* bc1 = (const float*)d_in[11];
    const float* Wc2 = (const float*)d_in[12];
    const float* rel = (const float*)d_in[13];

    float* ws = (float*)d_ws;
    float* q_cf  = ws;                 // 8388608 floats (B,C,H,W)
    float* xs_cl = ws + 8388608;       // 8388608 (B,H,W,C)
    float* k_cf  = ws + 16777216;      // 8388608
    float* v_cf  = ws + 25165824;      // 8388608
    float* W_eff = ws + 33554432;      // 6400
    float* b_eff = ws + 33560832;      // 2
    // P overlays k_cf (dead until k_proj(Wk)); W2/cst overlay v_cf (dead until k_proj(Wv))
    float* P     = k_cf;               // 4*50*16384 = 3276800 floats
    float* W2    = v_cf;               // 6400
    float* cst   = v_cf + 6400;        // 50
    float* outp  = (float*)d_out;

    hipLaunchKernelGGL(k_weff,  dim3(26),   dim3(256), 0, stream, Wc1, Wc2, bc1, W_eff, b_eff);
    hipLaunchKernelGGL(k_weff2, dim3(26),   dim3(256), 0, stream, W_eff, Wq, bq, W2, cst);
    hipLaunchKernelGGL(k_off,   dim3(1024), dim3(256), 0, stream, x, W2, cst, P);
    hipLaunchKernelGGL(k_sample,dim3(512),  dim3(256), 0, stream, P, b_eff, x, xs_cl);
    hipLaunchKernelGGL(k_proj,  dim3(1024), dim3(256), 0, stream, x, Wq, bq, (const float*)nullptr, q_cf);
    hipLaunchKernelGGL(k_proj,  dim3(1024), dim3(256), 0, stream, xs_cl, Wk, bk, (const float*)nullptr, k_cf);
    hipLaunchKernelGGL(k_proj,  dim3(1024), dim3(256), 0, stream, xs_cl, Wv, bv, rel, v_cf);
    hipLaunchKernelGGL(k_attn,  dim3(512),  dim3(256), 0, stream, q_cf, k_cf, v_cf, Wo, bo, outp);
}

// Round 3
// 289.381 us; speedup vs baseline: 1.7399x; 1.4310x over previous
//
#include <hip/hip_runtime.h>
#include <math.h>

// DeformAtten2D: B=4, H=W=C=128.
// R3: all GEMM-shaped phases moved to bf16 MFMA (16x16x32, fp32 accum).
//  - q/k/v projections: MFMA, bf16 channel-first plane outputs
//  - attention: S=q.kT (MFMA, direct-global frags) -> fp32 softmax in LDS ->
//    P bf16 -> O=P.v (v transposed to LDS) -> Y=O.WoT + bo fused epilogue
//  - offset path (k_off/k_sample) unchanged fp32 except bf16 xs output.
#define IMG 16384   // 128*128

typedef short short8  __attribute__((ext_vector_type(8)));
typedef float floatx4 __attribute__((ext_vector_type(4)));

__device__ __forceinline__ float4 ld4(const float* p) {
    return *reinterpret_cast<const float4*>(p);
}
__device__ __forceinline__ short f2bf(float f) {
    union { float f; unsigned u; } v; v.f = f;
    unsigned r = v.u + 0x7fffu + ((v.u >> 16) & 1u);   // RNE
    return (short)(r >> 16);
}

// ---------------------------------------------------------------------------
// Kernel 1a: W_eff[o50][c] = sum_o Wc2[t,o]*Wc1[o,c,tap]; b_eff[t]=Wc2[t]·bc1
// ---------------------------------------------------------------------------
__global__ void k_weff(const float* __restrict__ Wc1, const float* __restrict__ Wc2,
                       const float* __restrict__ bc1,
                       float* __restrict__ W_eff, float* __restrict__ b_eff) {
    int idx = blockIdx.x * 256 + threadIdx.x;
    if (idx < 6400) {
        int t   = idx / 3200;
        int rem = idx - t * 3200;
        int tap = rem >> 7;
        int c   = rem & 127;
        float acc = 0.f;
        for (int o = 0; o < 128; ++o)
            acc += Wc2[t * 128 + o] * Wc1[(o * 128 + c) * 25 + tap];
        W_eff[idx] = acc;
    } else if (idx < 6402) {
        int t = idx - 6400;
        float acc = 0.f;
        for (int o = 0; o < 128; ++o) acc += Wc2[t * 128 + o] * bc1[o];
        b_eff[t] = acc;
    }
}

// ---------------------------------------------------------------------------
// Kernel 1b: W2[o50][i] = sum_c W_eff[o50][c]*Wq[c][i]; cst[o50]=W_eff[o50]·bq
// ---------------------------------------------------------------------------
__global__ void k_weff2(const float* __restrict__ W_eff, const float* __restrict__ Wq,
                        const float* __restrict__ bq,
                        float* __restrict__ W2, float* __restrict__ cst) {
    int idx = blockIdx.x * 256 + threadIdx.x;
    if (idx < 6400) {
        int o = idx >> 7, i = idx & 127;
        float acc = 0.f;
        for (int c = 0; c < 128; ++c)
            acc += W_eff[o * 128 + c] * Wq[c * 128 + i];
        W2[idx] = acc;
    } else if (idx < 6450) {
        int o = idx - 6400;
        float acc = 0.f;
        for (int c = 0; c < 128; ++c) acc += W_eff[o * 128 + c] * bq[c];
        cst[o] = acc;
    }
}

// ---------------------------------------------------------------------------
// Kernel 1c: weights -> bf16 (wbf = [Wq|Wk|Wv|Wo], each 16384, row-major [o][k])
// ---------------------------------------------------------------------------
__global__ void k_prep(const float* __restrict__ Wq, const float* __restrict__ Wk,
                       const float* __restrict__ Wv, const float* __restrict__ Wo,
                       short* __restrict__ wbf) {
    int idx = blockIdx.x * 256 + threadIdx.x;   // 65536
    int sel = idx >> 14, i = idx & 16383;
    const float* s = (sel == 0) ? Wq : (sel == 1) ? Wk : (sel == 2) ? Wv : Wo;
    wbf[idx] = f2bf(s[i]);
}

// ---------------------------------------------------------------------------
// Kernel 1d: x (fp32, pixel-major channel-last) -> bf16 copy
// ---------------------------------------------------------------------------
__global__ void k_xcvt(const float* __restrict__ src, short* __restrict__ dst, int n8) {
    int i = blockIdx.x * 256 + threadIdx.x;
    if (i >= n8) return;
    const float* p = src + (size_t)i * 8;
    float4 a = ld4(p), b = ld4(p + 4);
    short8 o;
    o[0] = f2bf(a.x); o[1] = f2bf(a.y); o[2] = f2bf(a.z); o[3] = f2bf(a.w);
    o[4] = f2bf(b.x); o[5] = f2bf(b.y); o[6] = f2bf(b.z); o[7] = f2bf(b.w);
    *reinterpret_cast<short8*>(dst + (size_t)i * 8) = o;
}

// ---------------------------------------------------------------------------
// Kernel 2: MFMA projection.  A: bf16 (65536 px,128) channel-last.
//   Wb: bf16 (128 out,128 in).  out: bf16 channel-first planes (B,128,IMG).
//   Block = 128 px (one h row) x 128 out; 4 waves, 4x4 16x16 tiles each.
// ---------------------------------------------------------------------------
__launch_bounds__(256)
__global__ void k_projb(const short* __restrict__ A, const short* __restrict__ Wb,
                        const float* __restrict__ bias, const float* __restrict__ rel,
                        short* __restrict__ outp) {
    __shared__ __align__(16) short buf[128 * 136];   // [o][px] bf16 epilogue stage
    const int t = threadIdx.x;
    const int w = t >> 6, l = t & 63, l15 = l & 15, quad = l >> 4;
    const int mh = w >> 1, nh = w & 1;
    const int px0 = blockIdx.x * 128;
    const int b = px0 >> 14, hrow = (px0 & (IMG - 1)) >> 7;

    floatx4 acc[4][4];
#pragma unroll
    for (int im = 0; im < 4; ++im)
#pragma unroll
        for (int in = 0; in < 4; ++in)
            acc[im][in] = (floatx4){0.f, 0.f, 0.f, 0.f};

    const short* Ab = A + (size_t)px0 * 128;
#pragma unroll
    for (int kc = 0; kc < 128; kc += 32) {
        short8 af[4], bf_[4];
#pragma unroll
        for (int im = 0; im < 4; ++im)
            af[im] = *reinterpret_cast<const short8*>(
                Ab + (mh * 64 + im * 16 + l15) * 128 + kc + quad * 8);
#pragma unroll
        for (int in = 0; in < 4; ++in)
            bf_[in] = *reinterpret_cast<const short8*>(
                Wb + (nh * 64 + in * 16 + l15) * 128 + kc + quad * 8);
#pragma unroll
        for (int im = 0; im < 4; ++im)
#pragma unroll
            for (int in = 0; in < 4; ++in)
                acc[im][in] = __builtin_amdgcn_mfma_f32_16x16x32_bf16(
                    af[im], bf_[in], acc[im][in], 0, 0, 0);
    }

    float bv4[4];
#pragma unroll
    for (int in = 0; in < 4; ++in) {
        int o = nh * 64 + in * 16 + l15;
        bv4[in] = bias[o] + (rel ? rel[o * 128 + hrow] : 0.f);
    }
#pragma unroll
    for (int im = 0; im < 4; ++im)
#pragma unroll
        for (int in = 0; in < 4; ++in) {
            int col = nh * 64 + in * 16 + l15;
#pragma unroll
            for (int r = 0; r < 4; ++r) {
                int row = mh * 64 + im * 16 + quad * 4 + r;
                buf[col * 136 + row] = f2bf(acc[im][in][r] + bv4[in]);
            }
        }
    __syncthreads();
    for (int id = t; id < 2048; id += 256) {
        int o = id >> 4, seg = id & 15;
        *reinterpret_cast<short8*>(outp + ((size_t)(b * 128 + o)) * IMG + hrow * 128 + seg * 8)
            = *reinterpret_cast<const short8*>(&buf[o * 136 + seg * 8]);
    }
}

// ---------------------------------------------------------------------------
// Kernel 3a: P[b][o50][pix] = W2[o50]·x[pix] + cst[o50]  (fp32)
// ---------------------------------------------------------------------------
__launch_bounds__(256)
__global__ void k_off(const float* __restrict__ x, const float* __restrict__ W2,
                      const float* __restrict__ cst, float* __restrict__ P) {
    __shared__ float Wlds[128 * 68];
    __shared__ float Alds[32 * 68];
    const int t = threadIdx.x;
    const int pg = t & 15, og = t >> 4;
    const int p0 = blockIdx.x * 64;
    const int b = p0 >> 14, pix0 = p0 & (IMG - 1);

    for (int id = t; id < 128 * 64; id += 256) {
        int k = id >> 6, o = id & 63;
        Wlds[k * 68 + o] = (o < 50) ? W2[o * 128 + k] : 0.f;
    }
    float acc[4][4];
#pragma unroll
    for (int i = 0; i < 4; ++i)
#pragma unroll
        for (int j = 0; j < 4; ++j) acc[i][j] = 0.f;

    for (int kc = 0; kc < 128; kc += 32) {
        __syncthreads();
#pragma unroll
        for (int rep = 0; rep < 2; ++rep) {
            int id = rep * 256 + t;
            int m = id >> 3, k4 = (id & 7) * 4;
            float4 v = ld4(x + (size_t)(p0 + m) * 128 + kc + k4);
            Alds[(k4 + 0) * 68 + m] = v.x;
            Alds[(k4 + 1) * 68 + m] = v.y;
            Alds[(k4 + 2) * 68 + m] = v.z;
            Alds[(k4 + 3) * 68 + m] = v.w;
        }
        __syncthreads();
#pragma unroll
        for (int k = 0; k < 32; ++k) {
            float4 a = *reinterpret_cast<float4*>(&Alds[k * 68 + 4 * pg]);
            float4 wv = *reinterpret_cast<float4*>(&Wlds[(kc + k) * 68 + 4 * og]);
            float av[4] = {a.x, a.y, a.z, a.w};
            float wf[4] = {wv.x, wv.y, wv.z, wv.w};
#pragma unroll
            for (int i = 0; i < 4; ++i)
#pragma unroll
                for (int j = 0; j < 4; ++j)
                    acc[i][j] = fmaf(av[i], wf[j], acc[i][j]);
        }
    }
    __syncthreads();
#pragma unroll
    for (int j = 0; j < 4; ++j) {
        int o = 4 * og + j;
        float c = (o < 50) ? cst[o] : 0.f;
        *reinterpret_cast<float4*>(&Wlds[o * 68 + 4 * pg]) =
            make_float4(acc[0][j] + c, acc[1][j] + c, acc[2][j] + c, acc[3][j] + c);
    }
    __syncthreads();
    for (int id = t; id < 50 * 16; id += 256) {
        int o = id >> 4, px4 = (id & 15) * 4;
        float4 v = *reinterpret_cast<float4*>(&Wlds[o * 68 + px4]);
        *reinterpret_cast<float4*>(P + ((size_t)(b * 50 + o)) * IMG + pix0 + px4) = v;
    }
}

// ---------------------------------------------------------------------------
// Kernel 3b: shift-add taps -> tanh*5 -> bilinear sample; xs output bf16.
// ---------------------------------------------------------------------------
__launch_bounds__(256)
__global__ void k_sample(const float* __restrict__ P, const float* __restrict__ b_eff,
                         const float* __restrict__ x, short* __restrict__ xs) {
    __shared__ float rows[50 * 132];
    __shared__ float offs[256];
    const int t = threadIdx.x;
    const int bh = blockIdx.x;
    const int b = bh >> 7, h = bh & 127;

    for (int id = t; id < 50 * 32; id += 256) {
        int o = id >> 5, q4 = (id & 31) * 4;
        int di = (o % 25) / 5;
        int r = h + di - 2;
        float4 v = make_float4(0.f, 0.f, 0.f, 0.f);
        if (r >= 0 && r < 128)
            v = ld4(P + ((size_t)(b * 50 + o)) * IMG + r * 128 + q4);
        *reinterpret_cast<float4*>(&rows[o * 132 + q4]) = v;
    }
    __syncthreads();
    {
        int w = t & 127, tc = t >> 7;
        float acc = 0.f;
#pragma unroll
        for (int di = 0; di < 5; ++di)
#pragma unroll
            for (int dj = 0; dj < 5; ++dj) {
                int wj = w + dj - 2;
                if (wj >= 0 && wj < 128)
                    acc += rows[(tc * 25 + di * 5 + dj) * 132 + wj];
            }
        offs[tc * 128 + w] = tanhf(acc + b_eff[tc]) * 5.0f;
    }
    __syncthreads();

    const int wave = t >> 6, lane = t & 63;
    for (int px = wave; px < 128; px += 4) {
        float vx = (float)px + offs[px];
        float vy = (float)h  + offs[128 + px];
        float xg = vx * (128.0f / 127.0f) - 0.5f;
        float yg = vy * (128.0f / 127.0f) - 0.5f;
        float x0f = floorf(xg), y0f = floorf(yg);
        float fx = xg - x0f, fy = yg - y0f;
        int x0 = (int)x0f, y0 = (int)y0f;
        float s0 = 0.f, s1 = 0.f;
#pragma unroll
        for (int tap = 0; tap < 4; ++tap) {
            int xi = x0 + (tap & 1), yi = y0 + (tap >> 1);
            float wgt = ((tap & 1) ? fx : 1.f - fx) * ((tap >> 1) ? fy : 1.f - fy);
            if (xi >= 0 && xi < 128 && yi >= 0 && yi < 128) {
                const float* src = x + (((size_t)(b * 128 + yi)) * 128 + xi) * 128;
                s0 = fmaf(wgt, src[lane], s0);
                s1 = fmaf(wgt, src[lane + 64], s1);
            }
        }
        short* dst = xs + (((size_t)(b * 128 + h)) * 128 + px) * 128;
        dst[lane] = f2bf(s0);
        dst[lane + 64] = f2bf(s1);
    }
}

// ---------------------------------------------------------------------------
// Kernel 4: MFMA attention + fused output projection.  One head per block.
// ---------------------------------------------------------------------------
__launch_bounds__(256)
__global__ void k_attn2(const short* __restrict__ q_bf, const short* __restrict__ k_bf,
                        const short* __restrict__ v_bf, const short* __restrict__ WoB,
                        const float* __restrict__ bo, float* __restrict__ outp) {
    __shared__ __align__(16) float Sf[128 * 132];    // 67.6 KB; later O bf16
    __shared__ __align__(16) short Pb[128 * 136];    // 34.8 KB  P bf16
    __shared__ __align__(16) short vT[128 * 136];    // 34.8 KB  v transposed

    const int t = threadIdx.x;
    const int w = t >> 6, l = t & 63, l15 = l & 15, quad = l >> 4;
    const int mh = w >> 1, nh = w & 1;
    const size_t hb = (size_t)blockIdx.x * IMG;
    const short* qp = q_bf + hb;
    const short* kp = k_bf + hb;
    const short* vp = v_bf + hb;

    // ---- v -> vT (LDS), overlapped with phase 1 (no barrier until S done) ----
    for (int id = t; id < 2048; id += 256) {
        int j = id >> 4, seg = id & 15;
        short8 v8 = *reinterpret_cast<const short8*>(vp + j * 128 + seg * 8);
#pragma unroll
        for (int r = 0; r < 8; ++r)
            vT[(seg * 8 + r) * 136 + j] = v8[r];
    }

    floatx4 acc[4][4];
#pragma unroll
    for (int im = 0; im < 4; ++im)
#pragma unroll
        for (int in = 0; in < 4; ++in)
            acc[im][in] = (floatx4){0.f, 0.f, 0.f, 0.f};

    // ---- Phase 1: S = q·kT (direct-global bf16 frags) ----
#pragma unroll
    for (int kc = 0; kc < 128; kc += 32) {
        short8 af[4], bf_[4];
#pragma unroll
        for (int im = 0; im < 4; ++im)
            af[im] = *reinterpret_cast<const short8*>(
                qp + (mh * 64 + im * 16 + l15) * 128 + kc + quad * 8);
#pragma unroll
        for (int in = 0; in < 4; ++in)
            bf_[in] = *reinterpret_cast<const short8*>(
                kp + (nh * 64 + in * 16 + l15) * 128 + kc + quad * 8);
#pragma unroll
        for (int im = 0; im < 4; ++im)
#pragma unroll
            for (int in = 0; in < 4; ++in)
                acc[im][in] = __builtin_amdgcn_mfma_f32_16x16x32_bf16(
                    af[im], bf_[in], acc[im][in], 0, 0, 0);
    }
    const float scale = 0.08838834764831845f;
#pragma unroll
    for (int im = 0; im < 4; ++im)
#pragma unroll
        for (int in = 0; in < 4; ++in) {
            int col = nh * 64 + in * 16 + l15;
#pragma unroll
            for (int r = 0; r < 4; ++r) {
                int row = mh * 64 + im * 16 + quad * 4 + r;
                Sf[row * 132 + col] = acc[im][in][r] * scale;
            }
        }
    __syncthreads();   // S + vT complete

    // ---- softmax (row-wise, fp32), emit P bf16 ----
    if (t < 128) {
        float* row = &Sf[t * 132];
        float mx = -1e30f;
#pragma unroll 8
        for (int jj = 0; jj < 32; ++jj) {
            float4 v = *reinterpret_cast<float4*>(&row[jj * 4]);
            mx = fmaxf(mx, fmaxf(fmaxf(v.x, v.y), fmaxf(v.z, v.w)));
        }
        float ssum = 0.f;
#pragma unroll 8
        for (int jj = 0; jj < 32; ++jj) {
            float4 v = *reinterpret_cast<float4*>(&row[jj * 4]);
            v.x = __expf(v.x - mx); v.y = __expf(v.y - mx);
            v.z = __expf(v.z - mx); v.w = __expf(v.w - mx);
            *reinterpret_cast<float4*>(&row[jj * 4]) = v;
            ssum += v.x + v.y + v.z + v.w;
        }
        float inv = 1.0f / ssum;
        short* pr = &Pb[t * 136];
#pragma unroll 4
        for (int jj = 0; jj < 16; ++jj) {
            float4 a = *reinterpret_cast<float4*>(&row[jj * 8]);
            float4 b = *reinterpret_cast<float4*>(&row[jj * 8 + 4]);
            short8 o;
            o[0] = f2bf(a.x * inv); o[1] = f2bf(a.y * inv);
            o[2] = f2bf(a.z * inv); o[3] = f2bf(a.w * inv);
            o[4] = f2bf(b.x * inv); o[5] = f2bf(b.y * inv);
            o[6] = f2bf(b.z * inv); o[7] = f2bf(b.w * inv);
            *reinterpret_cast<short8*>(&pr[jj * 8]) = o;
        }
    }
    __syncthreads();

    // ---- Phase 2: O = P·v  (A from Pb LDS, B from vT LDS) ----
#pragma unroll
    for (int im = 0; im < 4; ++im)
#pragma unroll
        for (int in = 0; in < 4; ++in)
            acc[im][in] = (floatx4){0.f, 0.f, 0.f, 0.f};
#pragma unroll
    for (int kc = 0; kc < 128; kc += 32) {
        short8 af[4], bf_[4];
#pragma unroll
        for (int im = 0; im < 4; ++im)
            af[im] = *reinterpret_cast<const short8*>(
                &Pb[(mh * 64 + im * 16 + l15) * 136 + kc + quad * 8]);
#pragma unroll
        for (int in = 0; in < 4; ++in)
            bf_[in] = *reinterpret_cast<const short8*>(
                &vT[(nh * 64 + in * 16 + l15) * 136 + kc + quad * 8]);
#pragma unroll
        for (int im = 0; im < 4; ++im)
#pragma unroll
            for (int in = 0; in < 4; ++in)
                acc[im][in] = __builtin_amdgcn_mfma_f32_16x16x32_bf16(
                    af[im], bf_[in], acc[im][in], 0, 0, 0);
    }
    short* Obuf = reinterpret_cast<short*>(Sf);      // S dead -> O bf16 [i][136]
#pragma unroll
    for (int im = 0; im < 4; ++im)
#pragma unroll
        for (int in = 0; in < 4; ++in) {
            int col = nh * 64 + in * 16 + l15;       // d
#pragma unroll
            for (int r = 0; r < 4; ++r) {
                int row = mh * 64 + im * 16 + quad * 4 + r;   // i
                Obuf[row * 136 + col] = f2bf(acc[im][in][r]);
            }
        }
    __syncthreads();

    // ---- Phase 3: Y = O·WoT + bo ----
    float bb[4];
#pragma unroll
    for (int in = 0; in < 4; ++in) bb[in] = bo[nh * 64 + in * 16 + l15];
#pragma unroll
    for (int im = 0; im < 4; ++im)
#pragma unroll
        for (int in = 0; in < 4; ++in)
            acc[im][in] = (floatx4){0.f, 0.f, 0.f, 0.f};
#pragma unroll
    for (int kc = 0; kc < 128; kc += 32) {
        short8 af[4], bf_[4];
#pragma unroll
        for (int im = 0; im < 4; ++im)
            af[im] = *reinterpret_cast<const short8*>(
                &Obuf[(mh * 64 + im * 16 + l15) * 136 + kc + quad * 8]);
#pragma unroll
        for (int in = 0; in < 4; ++in)
            bf_[in] = *reinterpret_cast<const short8*>(
                WoB + (nh * 64 + in * 16 + l15) * 128 + kc + quad * 8);
#pragma unroll
        for (int im = 0; im < 4; ++im)
#pragma unroll
            for (int in = 0; in < 4; ++in)
                acc[im][in] = __builtin_amdgcn_mfma_f32_16x16x32_bf16(
                    af[im], bf_[in], acc[im][in], 0, 0, 0);
    }
#pragma unroll
    for (int im = 0; im < 4; ++im)
#pragma unroll
        for (int in = 0; in < 4; ++in) {
            int col = nh * 64 + in * 16 + l15;       // o
#pragma unroll
            for (int r = 0; r < 4; ++r) {
                int row = mh * 64 + im * 16 + quad * 4 + r;   // i
                outp[hb + (size_t)row * 128 + col] = acc[im][in][r] + bb[in];
            }
        }
}

// ---------------------------------------------------------------------------
extern "C" void kernel_launch(void* const* d_in, const int* in_sizes, int n_in,
                              void* d_out, int out_size, void* d_ws, size_t ws_size,
                              hipStream_t stream) {
    const float* x   = (const float*)d_in[0];
    const float* Wq  = (const float*)d_in[2];
    const float* bq  = (const float*)d_in[3];
    const float* Wk  = (const float*)d_in[4];
    const float* bk  = (const float*)d_in[5];
    const float* Wv  = (const float*)d_in[6];
    const float* bv  = (const float*)d_in[7];
    const float* Wo  = (const float*)d_in[8];
    const float* bo  = (const float*)d_in[9];
    const float* Wc1 = (const float*)d_in[10];
    const float* bc1 = (const float*)d_in[11];
    const float* Wc2 = (const float*)d_in[12];
    const float* rel = (const float*)d_in[13];

    char* wsb = (char*)d_ws;
    short* q_bf  = (short*)(wsb);                       // 16 MB each
    short* xs_bf = (short*)(wsb + 1ull * 16777216);
    short* k_bf  = (short*)(wsb + 2ull * 16777216);
    short* v_bf  = (short*)(wsb + 3ull * 16777216);
    short* x_bf  = (short*)(wsb + 4ull * 16777216);
    float* P     = (float*)(wsb + 5ull * 16777216);     // 13.1 MB
    float* W_eff = (float*)(wsb + 5ull * 16777216 + 13107200);
    float* b_eff = W_eff + 6400;
    float* W2    = b_eff + 16;
    float* cst   = W2 + 6400;
    short* wbf   = (short*)(cst + 64);                  // 4 x 16384 bf16
    float* outp  = (float*)d_out;

    hipLaunchKernelGGL(k_weff,  dim3(26),   dim3(256), 0, stream, Wc1, Wc2, bc1, W_eff, b_eff);
    hipLaunchKernelGGL(k_weff2, dim3(26),   dim3(256), 0, stream, W_eff, Wq, bq, W2, cst);
    hipLaunchKernelGGL(k_prep,  dim3(256),  dim3(256), 0, stream, Wq, Wk, Wv, Wo, wbf);
    hipLaunchKernelGGL(k_xcvt,  dim3(4096), dim3(256), 0, stream, x, x_bf, 1048576);
    hipLaunchKernelGGL(k_off,   dim3(1024), dim3(256), 0, stream, x, W2, cst, P);
    hipLaunchKernelGGL(k_sample,dim3(512),  dim3(256), 0, stream, P, b_eff, x, xs_bf);
    hipLaunchKernelGGL(k_projb, dim3(512),  dim3(256), 0, stream, x_bf,  wbf,         bq, (const float*)nullptr, q_bf);
    hipLaunchKernelGGL(k_projb, dim3(512),  dim3(256), 0, stream, xs_bf, wbf + 16384, bk, (const float*)nullptr, k_bf);
    hipLaunchKernelGGL(k_projb, dim3(512),  dim3(256), 0, stream, xs_bf, wbf + 32768, bv, rel,                   v_bf);
    hipLaunchKernelGGL(k_attn2, dim3(512),  dim3(256), 0, stream, q_bf, k_bf, v_bf, wbf + 49152, bo, outp);
}

// Round 4
// 245.960 us; speedup vs baseline: 2.0471x; 1.1765x over previous
//
#include <hip/hip_runtime.h>
#include <math.h>

// DeformAtten2D: B=4, H=W=C=128.
// R4: k_sample split into k_offs (offsets -> global) + k_gather (1M-thread
// bilinear gather from bf16 x, no LDS). k_attn3: register-shuffle softmax,
// S-fp32 LDS buffer eliminated (137KB -> 70KB LDS, 2 blocks/CU).
// Offset path (k_off, P, offsets) stays fp32 for accuracy.
#define IMG 16384   // 128*128

typedef short short8  __attribute__((ext_vector_type(8)));
typedef float floatx4 __attribute__((ext_vector_type(4)));

__device__ __forceinline__ float4 ld4(const float* p) {
    return *reinterpret_cast<const float4*>(p);
}
__device__ __forceinline__ short f2bf(float f) {
    union { float f; unsigned u; } v; v.f = f;
    unsigned r = v.u + 0x7fffu + ((v.u >> 16) & 1u);   // RNE
    return (short)(r >> 16);
}
__device__ __forceinline__ float bf2f(short s) {
    union { unsigned u; float f; } v;
    v.u = ((unsigned)(unsigned short)s) << 16;
    return v.f;
}

// ---------------------------------------------------------------------------
// Kernel 1a: W_eff[o50][c] = sum_o Wc2[t,o]*Wc1[o,c,tap]; b_eff[t]=Wc2[t]·bc1
// ---------------------------------------------------------------------------
__global__ void k_weff(const float* __restrict__ Wc1, const float* __restrict__ Wc2,
                       const float* __restrict__ bc1,
                       float* __restrict__ W_eff, float* __restrict__ b_eff) {
    int idx = blockIdx.x * 256 + threadIdx.x;
    if (idx < 6400) {
        int t   = idx / 3200;
        int rem = idx - t * 3200;
        int tap = rem >> 7;
        int c   = rem & 127;
        float acc = 0.f;
        for (int o = 0; o < 128; ++o)
            acc += Wc2[t * 128 + o] * Wc1[(o * 128 + c) * 25 + tap];
        W_eff[idx] = acc;
    } else if (idx < 6402) {
        int t = idx - 6400;
        float acc = 0.f;
        for (int o = 0; o < 128; ++o) acc += Wc2[t * 128 + o] * bc1[o];
        b_eff[t] = acc;
    }
}

// ---------------------------------------------------------------------------
// Kernel 1b: W2[o50][i] = sum_c W_eff[o50][c]*Wq[c][i]; cst[o50]=W_eff[o50]·bq
// ---------------------------------------------------------------------------
__global__ void k_weff2(const float* __restrict__ W_eff, const float* __restrict__ Wq,
                        const float* __restrict__ bq,
                        float* __restrict__ W2, float* __restrict__ cst) {
    int idx = blockIdx.x * 256 + threadIdx.x;
    if (idx < 6400) {
        int o = idx >> 7, i = idx & 127;
        float acc = 0.f;
        for (int c = 0; c < 128; ++c)
            acc += W_eff[o * 128 + c] * Wq[c * 128 + i];
        W2[idx] = acc;
    } else if (idx < 6450) {
        int o = idx - 6400;
        float acc = 0.f;
        for (int c = 0; c < 128; ++c) acc += W_eff[o * 128 + c] * bq[c];
        cst[o] = acc;
    }
}

// ---------------------------------------------------------------------------
// Kernel 1c: weights -> bf16 (wbf = [Wq|Wk|Wv|Wo], each 16384, row-major [o][k])
// ---------------------------------------------------------------------------
__global__ void k_prep(const float* __restrict__ Wq, const float* __restrict__ Wk,
                       const float* __restrict__ Wv, const float* __restrict__ Wo,
                       short* __restrict__ wbf) {
    int idx = blockIdx.x * 256 + threadIdx.x;   // 65536
    int sel = idx >> 14, i = idx & 16383;
    const float* s = (sel == 0) ? Wq : (sel == 1) ? Wk : (sel == 2) ? Wv : Wo;
    wbf[idx] = f2bf(s[i]);
}

// ---------------------------------------------------------------------------
// Kernel 1d: x fp32 -> bf16 copy
// ---------------------------------------------------------------------------
__global__ void k_xcvt(const float* __restrict__ src, short* __restrict__ dst, int n8) {
    int i = blockIdx.x * 256 + threadIdx.x;
    if (i >= n8) return;
    const float* p = src + (size_t)i * 8;
    float4 a = ld4(p), b = ld4(p + 4);
    short8 o;
    o[0] = f2bf(a.x); o[1] = f2bf(a.y); o[2] = f2bf(a.z); o[3] = f2bf(a.w);
    o[4] = f2bf(b.x); o[5] = f2bf(b.y); o[6] = f2bf(b.z); o[7] = f2bf(b.w);
    *reinterpret_cast<short8*>(dst + (size_t)i * 8) = o;
}

// ---------------------------------------------------------------------------
// Kernel 2: MFMA projection. A: bf16 (65536 px,128) channel-last.
//   out: bf16 channel-first planes (B,128,IMG).
// ---------------------------------------------------------------------------
__launch_bounds__(256)
__global__ void k_projb(const short* __restrict__ A, const short* __restrict__ Wb,
                        const float* __restrict__ bias, const float* __restrict__ rel,
                        short* __restrict__ outp) {
    __shared__ __align__(16) short buf[128 * 136];
    const int t = threadIdx.x;
    const int w = t >> 6, l = t & 63, l15 = l & 15, quad = l >> 4;
    const int mh = w >> 1, nh = w & 1;
    const int px0 = blockIdx.x * 128;
    const int b = px0 >> 14, hrow = (px0 & (IMG - 1)) >> 7;

    floatx4 acc[4][4];
#pragma unroll
    for (int im = 0; im < 4; ++im)
#pragma unroll
        for (int in = 0; in < 4; ++in)
            acc[im][in] = (floatx4){0.f, 0.f, 0.f, 0.f};

    const short* Ab = A + (size_t)px0 * 128;
#pragma unroll
    for (int kc = 0; kc < 128; kc += 32) {
        short8 af[4], bf_[4];
#pragma unroll
        for (int im = 0; im < 4; ++im)
            af[im] = *reinterpret_cast<const short8*>(
                Ab + (mh * 64 + im * 16 + l15) * 128 + kc + quad * 8);
#pragma unroll
        for (int in = 0; in < 4; ++in)
            bf_[in] = *reinterpret_cast<const short8*>(
                Wb + (nh * 64 + in * 16 + l15) * 128 + kc + quad * 8);
#pragma unroll
        for (int im = 0; im < 4; ++im)
#pragma unroll
            for (int in = 0; in < 4; ++in)
                acc[im][in] = __builtin_amdgcn_mfma_f32_16x16x32_bf16(
                    af[im], bf_[in], acc[im][in], 0, 0, 0);
    }

    float bv4[4];
#pragma unroll
    for (int in = 0; in < 4; ++in) {
        int o = nh * 64 + in * 16 + l15;
        bv4[in] = bias[o] + (rel ? rel[o * 128 + hrow] : 0.f);
    }
#pragma unroll
    for (int im = 0; im < 4; ++im)
#pragma unroll
        for (int in = 0; in < 4; ++in) {
            int col = nh * 64 + in * 16 + l15;
#pragma unroll
            for (int r = 0; r < 4; ++r) {
                int row = mh * 64 + im * 16 + quad * 4 + r;
                buf[col * 136 + row] = f2bf(acc[im][in][r] + bv4[in]);
            }
        }
    __syncthreads();
    for (int id = t; id < 2048; id += 256) {
        int o = id >> 4, seg = id & 15;
        *reinterpret_cast<short8*>(outp + ((size_t)(b * 128 + o)) * IMG + hrow * 128 + seg * 8)
            = *reinterpret_cast<const short8*>(&buf[o * 136 + seg * 8]);
    }
}

// ---------------------------------------------------------------------------
// Kernel 3a: P[b][o50][pix] = W2[o50]·x[pix] + cst[o50]  (fp32 — accuracy)
// ---------------------------------------------------------------------------
__launch_bounds__(256)
__global__ void k_off(const float* __restrict__ x, const float* __restrict__ W2,
                      const float* __restrict__ cst, float* __restrict__ P) {
    __shared__ float Wlds[128 * 68];
    __shared__ float Alds[32 * 68];
    const int t = threadIdx.x;
    const int pg = t & 15, og = t >> 4;
    const int p0 = blockIdx.x * 64;
    const int b = p0 >> 14, pix0 = p0 & (IMG - 1);

    for (int id = t; id < 128 * 64; id += 256) {
        int k = id >> 6, o = id & 63;
        Wlds[k * 68 + o] = (o < 50) ? W2[o * 128 + k] : 0.f;
    }
    float acc[4][4];
#pragma unroll
    for (int i = 0; i < 4; ++i)
#pragma unroll
        for (int j = 0; j < 4; ++j) acc[i][j] = 0.f;

    for (int kc = 0; kc < 128; kc += 32) {
        __syncthreads();
#pragma unroll
        for (int rep = 0; rep < 2; ++rep) {
            int id = rep * 256 + t;
            int m = id >> 3, k4 = (id & 7) * 4;
            float4 v = ld4(x + (size_t)(p0 + m) * 128 + kc + k4);
            Alds[(k4 + 0) * 68 + m] = v.x;
            Alds[(k4 + 1) * 68 + m] = v.y;
            Alds[(k4 + 2) * 68 + m] = v.z;
            Alds[(k4 + 3) * 68 + m] = v.w;
        }
        __syncthreads();
#pragma unroll
        for (int k = 0; k < 32; ++k) {
            float4 a = *reinterpret_cast<float4*>(&Alds[k * 68 + 4 * pg]);
            float4 wv = *reinterpret_cast<float4*>(&Wlds[(kc + k) * 68 + 4 * og]);
            float av[4] = {a.x, a.y, a.z, a.w};
            float wf[4] = {wv.x, wv.y, wv.z, wv.w};
#pragma unroll
            for (int i = 0; i < 4; ++i)
#pragma unroll
                for (int j = 0; j < 4; ++j)
                    acc[i][j] = fmaf(av[i], wf[j], acc[i][j]);
        }
    }
    __syncthreads();
#pragma unroll
    for (int j = 0; j < 4; ++j) {
        int o = 4 * og + j;
        float c = (o < 50) ? cst[o] : 0.f;
        *reinterpret_cast<float4*>(&Wlds[o * 68 + 4 * pg]) =
            make_float4(acc[0][j] + c, acc[1][j] + c, acc[2][j] + c, acc[3][j] + c);
    }
    __syncthreads();
    for (int id = t; id < 50 * 16; id += 256) {
        int o = id >> 4, px4 = (id & 15) * 4;
        float4 v = *reinterpret_cast<float4*>(&Wlds[o * 68 + px4]);
        *reinterpret_cast<float4*>(P + ((size_t)(b * 50 + o)) * IMG + pix0 + px4) = v;
    }
}

// ---------------------------------------------------------------------------
// Kernel 3b: per (b,h) row: 25-tap shift-add -> tanh*5 -> offsets to global.
// ---------------------------------------------------------------------------
__launch_bounds__(256)
__global__ void k_offs(const float* __restrict__ P, const float* __restrict__ b_eff,
                       float* __restrict__ offs) {
    __shared__ float rows[50 * 132];
    const int t = threadIdx.x;
    const int bh = blockIdx.x;
    const int b = bh >> 7, h = bh & 127;

    for (int id = t; id < 50 * 32; id += 256) {
        int o = id >> 5, q4 = (id & 31) * 4;
        int di = (o % 25) / 5;
        int r = h + di - 2;
        float4 v = make_float4(0.f, 0.f, 0.f, 0.f);
        if (r >= 0 && r < 128)
            v = ld4(P + ((size_t)(b * 50 + o)) * IMG + r * 128 + q4);
        *reinterpret_cast<float4*>(&rows[o * 132 + q4]) = v;
    }
    __syncthreads();
    int w = t & 127, tc = t >> 7;
    float acc = 0.f;
#pragma unroll
    for (int di = 0; di < 5; ++di)
#pragma unroll
        for (int dj = 0; dj < 5; ++dj) {
            int wj = w + dj - 2;
            if (wj >= 0 && wj < 128)
                acc += rows[(tc * 25 + di * 5 + dj) * 132 + wj];
        }
    offs[bh * 256 + tc * 128 + w] = tanhf(acc + b_eff[tc]) * 5.0f;
}

// ---------------------------------------------------------------------------
// Kernel 3c: bilinear gather from x_bf.  Thread = (pixel, 8-channel group).
// ---------------------------------------------------------------------------
__launch_bounds__(256)
__global__ void k_gather(const short* __restrict__ x_bf, const float* __restrict__ offs,
                         short* __restrict__ xs) {
    int idx = blockIdx.x * 256 + threadIdx.x;    // 1048576 total
    int px = idx >> 4, c8 = idx & 15;
    int b = px >> 14, pix = px & (IMG - 1);
    int h = pix >> 7, wpx = pix & 127;
    int bh = b * 128 + h;
    float ox = offs[bh * 256 + wpx];
    float oy = offs[bh * 256 + 128 + wpx];
    float xg = ((float)wpx + ox) * (128.0f / 127.0f) - 0.5f;
    float yg = ((float)h   + oy) * (128.0f / 127.0f) - 0.5f;
    float x0f = floorf(xg), y0f = floorf(yg);
    float fx = xg - x0f, fy = yg - y0f;
    int x0 = (int)x0f, y0 = (int)y0f;
    float s[8];
#pragma unroll
    for (int r = 0; r < 8; ++r) s[r] = 0.f;
#pragma unroll
    for (int tap = 0; tap < 4; ++tap) {
        int xi = x0 + (tap & 1), yi = y0 + (tap >> 1);
        float wgt = ((tap & 1) ? fx : 1.f - fx) * ((tap >> 1) ? fy : 1.f - fy);
        if (xi >= 0 && xi < 128 && yi >= 0 && yi < 128) {
            short8 v = *reinterpret_cast<const short8*>(
                x_bf + (((size_t)(b * 128 + yi)) * 128 + xi) * 128 + c8 * 8);
#pragma unroll
            for (int r = 0; r < 8; ++r) s[r] = fmaf(wgt, bf2f(v[r]), s[r]);
        }
    }
    short8 o;
#pragma unroll
    for (int r = 0; r < 8; ++r) o[r] = f2bf(s[r]);
    *reinterpret_cast<short8*>(xs + (size_t)px * 128 + c8 * 8) = o;
}

// ---------------------------------------------------------------------------
// Kernel 4: MFMA attention, register-shuffle softmax, fused output projection.
// LDS: Pb (P bf16, later O bf16) + vT + 2x128x2 reduction floats = ~71 KB.
// ---------------------------------------------------------------------------
__launch_bounds__(256)
__global__ void k_attn3(const short* __restrict__ q_bf, const short* __restrict__ k_bf,
                        const short* __restrict__ v_bf, const short* __restrict__ WoB,
                        const float* __restrict__ bo, float* __restrict__ outp) {
    __shared__ __align__(16) short Pb[128 * 136];    // P bf16; then O bf16
    __shared__ __align__(16) short vT[128 * 136];    // v transposed
    __shared__ float redm[2 * 128];
    __shared__ float reds[2 * 128];

    const int t = threadIdx.x;
    const int w = t >> 6, l = t & 63, l15 = l & 15, quad = l >> 4;
    const int mh = w >> 1, nh = w & 1;
    const size_t hb = (size_t)blockIdx.x * IMG;
    const short* qp = q_bf + hb;
    const short* kp = k_bf + hb;
    const short* vp = v_bf + hb;

    // ---- v -> vT (LDS), overlapped with phase 1 ----
    for (int id = t; id < 2048; id += 256) {
        int j = id >> 4, seg = id & 15;
        short8 v8 = *reinterpret_cast<const short8*>(vp + j * 128 + seg * 8);
#pragma unroll
        for (int r = 0; r < 8; ++r)
            vT[(seg * 8 + r) * 136 + j] = v8[r];
    }

    floatx4 acc[4][4];
#pragma unroll
    for (int im = 0; im < 4; ++im)
#pragma unroll
        for (int in = 0; in < 4; ++in)
            acc[im][in] = (floatx4){0.f, 0.f, 0.f, 0.f};

    // ---- Phase 1: S = q·kT (direct-global bf16 frags) ----
#pragma unroll
    for (int kc = 0; kc < 128; kc += 32) {
        short8 af[4], bf_[4];
#pragma unroll
        for (int im = 0; im < 4; ++im)
            af[im] = *reinterpret_cast<const short8*>(
                qp + (mh * 64 + im * 16 + l15) * 128 + kc + quad * 8);
#pragma unroll
        for (int in = 0; in < 4; ++in)
            bf_[in] = *reinterpret_cast<const short8*>(
                kp + (nh * 64 + in * 16 + l15) * 128 + kc + quad * 8);
#pragma unroll
        for (int im = 0; im < 4; ++im)
#pragma unroll
            for (int in = 0; in < 4; ++in)
                acc[im][in] = __builtin_amdgcn_mfma_f32_16x16x32_bf16(
                    af[im], bf_[in], acc[im][in], 0, 0, 0);
    }

    // ---- softmax in registers: rows owned per-lane in C layout ----
    const float scale = 0.08838834764831845f;
    float mloc[4][4];
#pragma unroll
    for (int im = 0; im < 4; ++im)
#pragma unroll
        for (int r = 0; r < 4; ++r) {
            float m = acc[im][0][r];
#pragma unroll
            for (int in = 1; in < 4; ++in) m = fmaxf(m, acc[im][in][r]);
            mloc[im][r] = m;
        }
#pragma unroll
    for (int mask = 1; mask < 16; mask <<= 1)
#pragma unroll
        for (int im = 0; im < 4; ++im)
#pragma unroll
            for (int r = 0; r < 4; ++r)
                mloc[im][r] = fmaxf(mloc[im][r], __shfl_xor(mloc[im][r], mask, 64));
    if (l15 == 0) {
#pragma unroll
        for (int im = 0; im < 4; ++im)
#pragma unroll
            for (int r = 0; r < 4; ++r)
                redm[nh * 128 + mh * 64 + im * 16 + quad * 4 + r] = mloc[im][r];
    }
    __syncthreads();
    float sloc[4][4];
#pragma unroll
    for (int im = 0; im < 4; ++im)
#pragma unroll
        for (int r = 0; r < 4; ++r) {
            int row = mh * 64 + im * 16 + quad * 4 + r;
            float m = fmaxf(redm[row], redm[128 + row]);
            float ss = 0.f;
#pragma unroll
            for (int in = 0; in < 4; ++in) {
                float e = __expf((acc[im][in][r] - m) * scale);
                acc[im][in][r] = e;
                ss += e;
            }
            sloc[im][r] = ss;
        }
#pragma unroll
    for (int mask = 1; mask < 16; mask <<= 1)
#pragma unroll
        for (int im = 0; im < 4; ++im)
#pragma unroll
            for (int r = 0; r < 4; ++r)
                sloc[im][r] += __shfl_xor(sloc[im][r], mask, 64);
    if (l15 == 0) {
#pragma unroll
        for (int im = 0; im < 4; ++im)
#pragma unroll
            for (int r = 0; r < 4; ++r)
                reds[nh * 128 + mh * 64 + im * 16 + quad * 4 + r] = sloc[im][r];
    }
    __syncthreads();
#pragma unroll
    for (int im = 0; im < 4; ++im)
#pragma unroll
        for (int r = 0; r < 4; ++r) {
            int row = mh * 64 + im * 16 + quad * 4 + r;
            float inv = 1.0f / (reds[row] + reds[128 + row]);
#pragma unroll
            for (int in = 0; in < 4; ++in) {
                int col = nh * 64 + in * 16 + l15;
                Pb[row * 136 + col] = f2bf(acc[im][in][r] * inv);
            }
        }
    __syncthreads();

    // ---- Phase 2: O = P·v  (A=Pb, B=vT) ----
#pragma unroll
    for (int im = 0; im < 4; ++im)
#pragma unroll
        for (int in = 0; in < 4; ++in)
            acc[im][in] = (floatx4){0.f, 0.f, 0.f, 0.f};
#pragma unroll
    for (int kc = 0; kc < 128; kc += 32) {
        short8 af[4], bf_[4];
#pragma unroll
        for (int im = 0; im < 4; ++im)
            af[im] = *reinterpret_cast<const short8*>(
                &Pb[(mh * 64 + im * 16 + l15) * 136 + kc + quad * 8]);
#pragma unroll
        for (int in = 0; in < 4; ++in)
            bf_[in] = *reinterpret_cast<const short8*>(
                &vT[(nh * 64 + in * 16 + l15) * 136 + kc + quad * 8]);
#pragma unroll
        for (int im = 0; im < 4; ++im)
#pragma unroll
            for (int in = 0; in < 4; ++in)
                acc[im][in] = __builtin_amdgcn_mfma_f32_16x16x32_bf16(
                    af[im], bf_[in], acc[im][in], 0, 0, 0);
    }
    __syncthreads();          // all P reads done before overwriting Pb with O
#pragma unroll
    for (int im = 0; im < 4; ++im)
#pragma unroll
        for (int in = 0; in < 4; ++in) {
            int col = nh * 64 + in * 16 + l15;
#pragma unroll
            for (int r = 0; r < 4; ++r) {
                int row = mh * 64 + im * 16 + quad * 4 + r;
                Pb[row * 136 + col] = f2bf(acc[im][in][r]);
            }
        }
    __syncthreads();

    // ---- Phase 3: Y = O·WoT + bo ----
    float bb[4];
#pragma unroll
    for (int in = 0; in < 4; ++in) bb[in] = bo[nh * 64 + in * 16 + l15];
#pragma unroll
    for (int im = 0; im < 4; ++im)
#pragma unroll
        for (int in = 0; in < 4; ++in)
            acc[im][in] = (floatx4){0.f, 0.f, 0.f, 0.f};
#pragma unroll
    for (int kc = 0; kc < 128; kc += 32) {
        short8 af[4], bf_[4];
#pragma unroll
        for (int im = 0; im < 4; ++im)
            af[im] = *reinterpret_cast<const short8*>(
                &Pb[(mh * 64 + im * 16 + l15) * 136 + kc + quad * 8]);
#pragma unroll
        for (int in = 0; in < 4; ++in)
            bf_[in] = *reinterpret_cast<const short8*>(
                WoB + (nh * 64 + in * 16 + l15) * 128 + kc + quad * 8);
#pragma unroll
        for (int im = 0; im < 4; ++im)
#pragma unroll
            for (int in = 0; in < 4; ++in)
                acc[im][in] = __builtin_amdgcn_mfma_f32_16x16x32_bf16(
                    af[im], bf_[in], acc[im][in], 0, 0, 0);
    }
#pragma unroll
    for (int im = 0; im < 4; ++im)
#pragma unroll
        for (int in = 0; in < 4; ++in) {
            int col = nh * 64 + in * 16 + l15;
#pragma unroll
            for (int r = 0; r < 4; ++r) {
                int row = mh * 64 + im * 16 + quad * 4 + r;
                outp[hb + (size_t)row * 128 + col] = acc[im][in][r] + bb[in];
            }
        }
}

// ---------------------------------------------------------------------------
extern "C" void kernel_launch(void* const* d_in, const int* in_sizes, int n_in,
                              void* d_out, int out_size, void* d_ws, size_t ws_size,
                              hipStream_t stream) {
    const float* x   = (const float*)d_in[0];
    const float* Wq  = (const float*)d_in[2];
    const float* bq  = (const float*)d_in[3];
    const float* Wk  = (const float*)d_in[4];
    const float* bk  = (const float*)d_in[5];
    const float* Wv  = (const float*)d_in[6];
    const float* bv  = (const float*)d_in[7];
    const float* Wo  = (const float*)d_in[8];
    const float* bo  = (const float*)d_in[9];
    const float* Wc1 = (const float*)d_in[10];
    const float* bc1 = (const float*)d_in[11];
    const float* Wc2 = (const float*)d_in[12];
    const float* rel = (const float*)d_in[13];

    char* wsb = (char*)d_ws;
    short* q_bf  = (short*)(wsb);                       // 16 MB each
    short* xs_bf = (short*)(wsb + 1ull * 16777216);
    short* k_bf  = (short*)(wsb + 2ull * 16777216);
    short* v_bf  = (short*)(wsb + 3ull * 16777216);
    short* x_bf  = (short*)(wsb + 4ull * 16777216);
    float* P     = (float*)(wsb + 5ull * 16777216);     // 13.1 MB
    float* W_eff = (float*)(wsb + 5ull * 16777216 + 13107200);
    float* b_eff = W_eff + 6400;
    float* W2    = b_eff + 16;
    float* cst   = W2 + 6400;
    short* wbf   = (short*)(cst + 64);                  // 4 x 16384 bf16
    float* offs  = (float*)(wbf + 65536);               // 131072 floats
    float* outp  = (float*)d_out;

    hipLaunchKernelGGL(k_weff,  dim3(26),   dim3(256), 0, stream, Wc1, Wc2, bc1, W_eff, b_eff);
    hipLaunchKernelGGL(k_weff2, dim3(26),   dim3(256), 0, stream, W_eff, Wq, bq, W2, cst);
    hipLaunchKernelGGL(k_prep,  dim3(256),  dim3(256), 0, stream, Wq, Wk, Wv, Wo, wbf);
    hipLaunchKernelGGL(k_xcvt,  dim3(4096), dim3(256), 0, stream, x, x_bf, 1048576);
    hipLaunchKernelGGL(k_off,   dim3(1024), dim3(256), 0, stream, x, W2, cst, P);
    hipLaunchKernelGGL(k_offs,  dim3(512),  dim3(256), 0, stream, P, b_eff, offs);
    hipLaunchKernelGGL(k_gather,dim3(4096), dim3(256), 0, stream, x_bf, offs, xs_bf);
    hipLaunchKernelGGL(k_projb, dim3(512),  dim3(256), 0, stream, x_bf,  wbf,         bq, (const float*)nullptr, q_bf);
    hipLaunchKernelGGL(k_projb, dim3(512),  dim3(256), 0, stream, xs_bf, wbf + 16384, bk, (const float*)nullptr, k_bf);
    hipLaunchKernelGGL(k_projb, dim3(512),  dim3(256), 0, stream, xs_bf, wbf + 32768, bv, rel,                   v_bf);
    hipLaunchKernelGGL(k_attn3, dim3(512),  dim3(256), 0, stream, q_bf, k_bf, v_bf, wbf + 49152, bo, outp);
}

// Round 5
// 223.351 us; speedup vs baseline: 2.2543x; 1.1012x over previous
//
#include <hip/hip_runtime.h>
#include <math.h>

// DeformAtten2D: B=4, H=W=C=128.
// R5: launch-count 11 -> 5. k_fused does offsets(conv shift-add) -> bilinear
// gather (LDS only, xs never hits HBM) -> q/k/v MFMA projections per (b,h)
// row. k_wprep = both weight contractions in one launch. k_cvt = x+weights
// bf16 conversion in one launch. k_off (fp32 offset GEMM) and k_attn3
// unchanged. Numerics identical to R4.
#define IMG 16384   // 128*128

typedef short short8  __attribute__((ext_vector_type(8)));
typedef float floatx4 __attribute__((ext_vector_type(4)));

__device__ __forceinline__ float4 ld4(const float* p) {
    return *reinterpret_cast<const float4*>(p);
}
__device__ __forceinline__ short f2bf(float f) {
    union { float f; unsigned u; } v; v.f = f;
    unsigned r = v.u + 0x7fffu + ((v.u >> 16) & 1u);   // RNE
    return (short)(r >> 16);
}
__device__ __forceinline__ float bf2f(short s) {
    union { unsigned u; float f; } v;
    v.u = ((unsigned)(unsigned short)s) << 16;
    return v.f;
}

// ---------------------------------------------------------------------------
// Kernel 1: one block per o50=(t,tap).  U[c]=sum_o Wc2[t,o]*Wc1[o,c,tap];
//   W2[o50,i]=sum_c U[c]*Wq[c,i]; cst[o50]=U·bq; b_eff[t]=Wc2[t]·bc1 (tap==0).
// ---------------------------------------------------------------------------
__launch_bounds__(256)
__global__ void k_wprep(const float* __restrict__ Wc1, const float* __restrict__ Wc2,
                        const float* __restrict__ bc1, const float* __restrict__ Wq,
                        const float* __restrict__ bq,
                        float* __restrict__ W2, float* __restrict__ cst,
                        float* __restrict__ b_eff) {
    __shared__ float U[128];
    __shared__ float red[256];
    __shared__ float wc2[128];
    __shared__ float bql[128];
    const int tt = blockIdx.x;               // 0..49
    const int tch = tt / 25, tap = tt % 25;
    const int t = threadIdx.x;
    if (t < 128) { wc2[t] = Wc2[tch * 128 + t]; bql[t] = bq[t]; }
    __syncthreads();
    const int c = t & 127, half = t >> 7;
    float p = 0.f;
    for (int o = half * 64; o < half * 64 + 64; ++o)
        p += wc2[o] * Wc1[(o * 128 + c) * 25 + tap];
    red[half * 128 + c] = p;
    __syncthreads();
    if (t < 128) U[t] = red[t] + red[128 + t];
    __syncthreads();
    float p2 = 0.f;
    for (int cc = half * 64; cc < half * 64 + 64; ++cc)
        p2 += U[cc] * Wq[cc * 128 + c];
    red[half * 128 + c] = p2;
    __syncthreads();
    if (t < 128) W2[tt * 128 + t] = red[t] + red[128 + t];
    if (t < 128) red[t] = U[t] * bql[t];
    __syncthreads();
    if (t == 0) {
        float s = 0.f;
        for (int j = 0; j < 128; ++j) s += red[j];
        cst[tt] = s;
    }
    if (tap == 0) {
        __syncthreads();
        if (t < 128) red[t] = wc2[t] * bc1[t];
        __syncthreads();
        if (t == 0) {
            float s = 0.f;
            for (int j = 0; j < 128; ++j) s += red[j];
            b_eff[tch] = s;
        }
    }
}

// ---------------------------------------------------------------------------
// Kernel 2: x fp32 -> bf16 (blocks 0..4095) + weights -> bf16 (blocks 4096+).
//   wbf = [Wq|Wk|Wv|Wo], each 16384, row-major.
// ---------------------------------------------------------------------------
__launch_bounds__(256)
__global__ void k_cvt(const float* __restrict__ x,
                      const float* __restrict__ Wq, const float* __restrict__ Wk,
                      const float* __restrict__ Wv, const float* __restrict__ Wo,
                      short* __restrict__ x_bf, short* __restrict__ wbf) {
    const int gid = blockIdx.x;
    if (gid < 4096) {
        int i = gid * 256 + threadIdx.x;     // < 1048576 groups of 8
        const float* p = x + (size_t)i * 8;
        float4 a = ld4(p), b = ld4(p + 4);
        short8 o;
        o[0] = f2bf(a.x); o[1] = f2bf(a.y); o[2] = f2bf(a.z); o[3] = f2bf(a.w);
        o[4] = f2bf(b.x); o[5] = f2bf(b.y); o[6] = f2bf(b.z); o[7] = f2bf(b.w);
        *reinterpret_cast<short8*>(x_bf + (size_t)i * 8) = o;
    } else {
        int i = (gid - 4096) * 256 + threadIdx.x;   // < 8192
        int base = i * 8;
        int sel = base >> 14, off = base & 16383;
        const float* s = (sel == 0) ? Wq : (sel == 1) ? Wk : (sel == 2) ? Wv : Wo;
        float4 a = ld4(s + off), b = ld4(s + off + 4);
        short8 o;
        o[0] = f2bf(a.x); o[1] = f2bf(a.y); o[2] = f2bf(a.z); o[3] = f2bf(a.w);
        o[4] = f2bf(b.x); o[5] = f2bf(b.y); o[6] = f2bf(b.z); o[7] = f2bf(b.w);
        *reinterpret_cast<short8*>(wbf + base) = o;
    }
}

// ---------------------------------------------------------------------------
// Kernel 3: P[b][o50][pix] = W2[o50]·x[pix] + cst[o50]  (fp32 — accuracy)
// ---------------------------------------------------------------------------
__launch_bounds__(256)
__global__ void k_off(const float* __restrict__ x, const float* __restrict__ W2,
                      const float* __restrict__ cst, float* __restrict__ P) {
    __shared__ float Wlds[128 * 68];
    __shared__ float Alds[32 * 68];
    const int t = threadIdx.x;
    const int pg = t & 15, og = t >> 4;
    const int p0 = blockIdx.x * 64;
    const int b = p0 >> 14, pix0 = p0 & (IMG - 1);

    for (int id = t; id < 128 * 64; id += 256) {
        int k = id >> 6, o = id & 63;
        Wlds[k * 68 + o] = (o < 50) ? W2[o * 128 + k] : 0.f;
    }
    float acc[4][4];
#pragma unroll
    for (int i = 0; i < 4; ++i)
#pragma unroll
        for (int j = 0; j < 4; ++j) acc[i][j] = 0.f;

    for (int kc = 0; kc < 128; kc += 32) {
        __syncthreads();
#pragma unroll
        for (int rep = 0; rep < 2; ++rep) {
            int id = rep * 256 + t;
            int m = id >> 3, k4 = (id & 7) * 4;
            float4 v = ld4(x + (size_t)(p0 + m) * 128 + kc + k4);
            Alds[(k4 + 0) * 68 + m] = v.x;
            Alds[(k4 + 1) * 68 + m] = v.y;
            Alds[(k4 + 2) * 68 + m] = v.z;
            Alds[(k4 + 3) * 68 + m] = v.w;
        }
        __syncthreads();
#pragma unroll
        for (int k = 0; k < 32; ++k) {
            float4 a = *reinterpret_cast<float4*>(&Alds[k * 68 + 4 * pg]);
            float4 wv = *reinterpret_cast<float4*>(&Wlds[(kc + k) * 68 + 4 * og]);
            float av[4] = {a.x, a.y, a.z, a.w};
            float wf[4] = {wv.x, wv.y, wv.z, wv.w};
#pragma unroll
            for (int i = 0; i < 4; ++i)
#pragma unroll
                for (int j = 0; j < 4; ++j)
                    acc[i][j] = fmaf(av[i], wf[j], acc[i][j]);
        }
    }
    __syncthreads();
#pragma unroll
    for (int j = 0; j < 4; ++j) {
        int o = 4 * og + j;
        float c = (o < 50) ? cst[o] : 0.f;
        *reinterpret_cast<float4*>(&Wlds[o * 68 + 4 * pg]) =
            make_float4(acc[0][j] + c, acc[1][j] + c, acc[2][j] + c, acc[3][j] + c);
    }
    __syncthreads();
    for (int id = t; id < 50 * 16; id += 256) {
        int o = id >> 4, px4 = (id & 15) * 4;
        float4 v = *reinterpret_cast<float4*>(&Wlds[o * 68 + px4]);
        *reinterpret_cast<float4*>(P + ((size_t)(b * 50 + o)) * IMG + pix0 + px4) = v;
    }
}

// ---------------------------------------------------------------------------
// Kernel 4: FUSED per (b,h) row:
//   A: conv shift-add of P -> tanh*5 offsets (LDS)
//   B: bilinear gather from x_bf -> xsT tile (LDS, never to HBM)
//   C: x row h -> xrow tile (LDS)
//   D: 3 MFMA GEMMs (q from xrow; k,v from xsT) -> bf16 channel-first planes
// LDS: 34816 (xrow/rowsP/stage union) + 34816 (xsT) + 1024 (offs) = 69 KB.
// ---------------------------------------------------------------------------
__launch_bounds__(256)
__global__ void k_fused(const float* __restrict__ P, const float* __restrict__ b_eff,
                        const short* __restrict__ x_bf, const short* __restrict__ wbf,
                        const float* __restrict__ bq, const float* __restrict__ bk,
                        const float* __restrict__ bv, const float* __restrict__ rel,
                        short* __restrict__ q_bf, short* __restrict__ k_bf,
                        short* __restrict__ v_bf) {
    __shared__ __align__(16) char smem[70656];
    float* rowsP  = (float*)smem;                // phase A only (26400 B)
    short* xrow   = (short*)smem;                // phase C/D (34816 B, aliases)
    short* bufS   = (short*)smem;                // epilogue stage (aliases)
    short* xsT    = (short*)(smem + 34816);      // gathered tile
    float* offs_l = (float*)(smem + 69632);      // [2][128]

    const int t = threadIdx.x;
    const int w = t >> 6, l = t & 63, l15 = l & 15, quad = l >> 4;
    const int mh = w >> 1, nh = w & 1;
    const int bh = blockIdx.x;
    const int b = bh >> 7, h = bh & 127;

    // ---- Phase A: stage P rows (5-row halo), 25-tap shift-add, tanh*5 ----
    for (int id = t; id < 1600; id += 256) {
        int o = id >> 5, q4 = (id & 31) * 4;
        int di = (o % 25) / 5;
        int r = h + di - 2;
        float4 v = make_float4(0.f, 0.f, 0.f, 0.f);
        if (r >= 0 && r < 128)
            v = ld4(P + ((size_t)(b * 50 + o)) * IMG + r * 128 + q4);
        *reinterpret_cast<float4*>(&rowsP[o * 132 + q4]) = v;
    }
    __syncthreads();
    {
        int wp = t & 127, tc = t >> 7;
        float acc = 0.f;
#pragma unroll
        for (int di = 0; di < 5; ++di)
#pragma unroll
            for (int dj = 0; dj < 5; ++dj) {
                int wj = wp + dj - 2;
                if (wj >= 0 && wj < 128)
                    acc += rowsP[(tc * 25 + di * 5 + dj) * 132 + wj];
            }
        offs_l[tc * 128 + wp] = tanhf(acc + b_eff[tc]) * 5.0f;
    }
    __syncthreads();   // offs ready; rowsP dead

    // ---- Phase C: x row h -> xrow ----
    for (int id = t; id < 2048; id += 256) {
        int px = id >> 4, c8 = id & 15;
        *reinterpret_cast<short8*>(&xrow[px * 136 + c8 * 8]) =
            *reinterpret_cast<const short8*>(
                x_bf + (((size_t)(b * 128 + h)) * 128 + px) * 128 + c8 * 8);
    }
    // ---- Phase B: bilinear gather -> xsT ----
    for (int id = t; id < 2048; id += 256) {
        int px = id >> 4, c8 = id & 15;
        float ox = offs_l[px];
        float oy = offs_l[128 + px];
        float xg = ((float)px + ox) * (128.0f / 127.0f) - 0.5f;
        float yg = ((float)h  + oy) * (128.0f / 127.0f) - 0.5f;
        float x0f = floorf(xg), y0f = floorf(yg);
        float fx = xg - x0f, fy = yg - y0f;
        int x0 = (int)x0f, y0 = (int)y0f;
        float s[8];
#pragma unroll
        for (int r = 0; r < 8; ++r) s[r] = 0.f;
#pragma unroll
        for (int tap = 0; tap < 4; ++tap) {
            int xi = x0 + (tap & 1), yi = y0 + (tap >> 1);
            float wgt = ((tap & 1) ? fx : 1.f - fx) * ((tap >> 1) ? fy : 1.f - fy);
            if (xi >= 0 && xi < 128 && yi >= 0 && yi < 128) {
                short8 v = *reinterpret_cast<const short8*>(
                    x_bf + (((size_t)(b * 128 + yi)) * 128 + xi) * 128 + c8 * 8);
#pragma unroll
                for (int r = 0; r < 8; ++r) s[r] = fmaf(wgt, bf2f(v[r]), s[r]);
            }
        }
        short8 o;
#pragma unroll
        for (int r = 0; r < 8; ++r) o[r] = f2bf(s[r]);
        *reinterpret_cast<short8*>(&xsT[px * 136 + c8 * 8]) = o;
    }
    __syncthreads();

    // ---- Phase D: three 128x128x128 MFMA GEMMs ----
#pragma unroll
    for (int g = 0; g < 3; ++g) {
        const short* Asrc = (g == 0) ? xrow : xsT;
        const short* Wg   = wbf + g * 16384;
        const float* bias = (g == 0) ? bq : (g == 1) ? bk : bv;
        short* outg       = (g == 0) ? q_bf : (g == 1) ? k_bf : v_bf;

        floatx4 acc[4][4];
#pragma unroll
        for (int im = 0; im < 4; ++im)
#pragma unroll
            for (int in = 0; in < 4; ++in)
                acc[im][in] = (floatx4){0.f, 0.f, 0.f, 0.f};
#pragma unroll
        for (int kc = 0; kc < 128; kc += 32) {
            short8 af[4], bf_[4];
#pragma unroll
            for (int im = 0; im < 4; ++im)
                af[im] = *reinterpret_cast<const short8*>(
                    &Asrc[(mh * 64 + im * 16 + l15) * 136 + kc + quad * 8]);
#pragma unroll
            for (int in = 0; in < 4; ++in)
                bf_[in] = *reinterpret_cast<const short8*>(
                    Wg + (nh * 64 + in * 16 + l15) * 128 + kc + quad * 8);
#pragma unroll
            for (int im = 0; im < 4; ++im)
#pragma unroll
                for (int in = 0; in < 4; ++in)
                    acc[im][in] = __builtin_amdgcn_mfma_f32_16x16x32_bf16(
                        af[im], bf_[in], acc[im][in], 0, 0, 0);
        }
        float bb[4];
#pragma unroll
        for (int in = 0; in < 4; ++in) {
            int o = nh * 64 + in * 16 + l15;
            bb[in] = bias[o] + ((g == 2) ? rel[o * 128 + h] : 0.f);
        }
        __syncthreads();   // Asrc reads done (g=0: xrow about to be overwritten)
#pragma unroll
        for (int im = 0; im < 4; ++im)
#pragma unroll
            for (int in = 0; in < 4; ++in) {
                int col = nh * 64 + in * 16 + l15;
#pragma unroll
                for (int r = 0; r < 4; ++r) {
                    int row = mh * 64 + im * 16 + quad * 4 + r;
                    bufS[col * 136 + row] = f2bf(acc[im][in][r] + bb[in]);
                }
            }
        __syncthreads();
        for (int id = t; id < 2048; id += 256) {
            int o = id >> 4, seg = id & 15;
            *reinterpret_cast<short8*>(
                outg + ((size_t)(b * 128 + o)) * IMG + h * 128 + seg * 8)
                = *reinterpret_cast<const short8*>(&bufS[o * 136 + seg * 8]);
        }
        __syncthreads();   // bufS reads done before next g's staging
    }
}

// ---------------------------------------------------------------------------
// Kernel 5: MFMA attention, register-shuffle softmax, fused output projection.
// ---------------------------------------------------------------------------
__launch_bounds__(256)
__global__ void k_attn3(const short* __restrict__ q_bf, const short* __restrict__ k_bf,
                        const short* __restrict__ v_bf, const short* __restrict__ WoB,
                        const float* __restrict__ bo, float* __restrict__ outp) {
    __shared__ __align__(16) short Pb[128 * 136];    // P bf16; then O bf16
    __shared__ __align__(16) short vT[128 * 136];    // v transposed
    __shared__ float redm[2 * 128];
    __shared__ float reds[2 * 128];

    const int t = threadIdx.x;
    const int w = t >> 6, l = t & 63, l15 = l & 15, quad = l >> 4;
    const int mh = w >> 1, nh = w & 1;
    const size_t hb = (size_t)blockIdx.x * IMG;
    const short* qp = q_bf + hb;
    const short* kp = k_bf + hb;
    const short* vp = v_bf + hb;

    for (int id = t; id < 2048; id += 256) {
        int j = id >> 4, seg = id & 15;
        short8 v8 = *reinterpret_cast<const short8*>(vp + j * 128 + seg * 8);
#pragma unroll
        for (int r = 0; r < 8; ++r)
            vT[(seg * 8 + r) * 136 + j] = v8[r];
    }

    floatx4 acc[4][4];
#pragma unroll
    for (int im = 0; im < 4; ++im)
#pragma unroll
        for (int in = 0; in < 4; ++in)
            acc[im][in] = (floatx4){0.f, 0.f, 0.f, 0.f};

#pragma unroll
    for (int kc = 0; kc < 128; kc += 32) {
        short8 af[4], bf_[4];
#pragma unroll
        for (int im = 0; im < 4; ++im)
            af[im] = *reinterpret_cast<const short8*>(
                qp + (mh * 64 + im * 16 + l15) * 128 + kc + quad * 8);
#pragma unroll
        for (int in = 0; in < 4; ++in)
            bf_[in] = *reinterpret_cast<const short8*>(
                kp + (nh * 64 + in * 16 + l15) * 128 + kc + quad * 8);
#pragma unroll
        for (int im = 0; im < 4; ++im)
#pragma unroll
            for (int in = 0; in < 4; ++in)
                acc[im][in] = __builtin_amdgcn_mfma_f32_16x16x32_bf16(
                    af[im], bf_[in], acc[im][in], 0, 0, 0);
    }

    const float scale = 0.08838834764831845f;
    float mloc[4][4];
#pragma unroll
    for (int im = 0; im < 4; ++im)
#pragma unroll
        for (int r = 0; r < 4; ++r) {
            float m = acc[im][0][r];
#pragma unroll
            for (int in = 1; in < 4; ++in) m = fmaxf(m, acc[im][in][r]);
            mloc[im][r] = m;
        }
#pragma unroll
    for (int mask = 1; mask < 16; mask <<= 1)
#pragma unroll
        for (int im = 0; im < 4; ++im)
#pragma unroll
            for (int r = 0; r < 4; ++r)
                mloc[im][r] = fmaxf(mloc[im][r], __shfl_xor(mloc[im][r], mask, 64));
    if (l15 == 0) {
#pragma unroll
        for (int im = 0; im < 4; ++im)
#pragma unroll
            for (int r = 0; r < 4; ++r)
                redm[nh * 128 + mh * 64 + im * 16 + quad * 4 + r] = mloc[im][r];
    }
    __syncthreads();
    float sloc[4][4];
#pragma unroll
    for (int im = 0; im < 4; ++im)
#pragma unroll
        for (int r = 0; r < 4; ++r) {
            int row = mh * 64 + im * 16 + quad * 4 + r;
            float m = fmaxf(redm[row], redm[128 + row]);
            float ss = 0.f;
#pragma unroll
            for (int in = 0; in < 4; ++in) {
                float e = __expf((acc[im][in][r] - m) * scale);
                acc[im][in][r] = e;
                ss += e;
            }
            sloc[im][r] = ss;
        }
#pragma unroll
    for (int mask = 1; mask < 16; mask <<= 1)
#pragma unroll
        for (int im = 0; im < 4; ++im)
#pragma unroll
            for (int r = 0; r < 4; ++r)
                sloc[im][r] += __shfl_xor(sloc[im][r], mask, 64);
    if (l15 == 0) {
#pragma unroll
        for (int im = 0; im < 4; ++im)
#pragma unroll
            for (int r = 0; r < 4; ++r)
                reds[nh * 128 + mh * 64 + im * 16 + quad * 4 + r] = sloc[im][r];
    }
    __syncthreads();
#pragma unroll
    for (int im = 0; im < 4; ++im)
#pragma unroll
        for (int r = 0; r < 4; ++r) {
            int row = mh * 64 + im * 16 + quad * 4 + r;
            float inv = 1.0f / (reds[row] + reds[128 + row]);
#pragma unroll
            for (int in = 0; in < 4; ++in) {
                int col = nh * 64 + in * 16 + l15;
                Pb[row * 136 + col] = f2bf(acc[im][in][r] * inv);
            }
        }
    __syncthreads();

#pragma unroll
    for (int im = 0; im < 4; ++im)
#pragma unroll
        for (int in = 0; in < 4; ++in)
            acc[im][in] = (floatx4){0.f, 0.f, 0.f, 0.f};
#pragma unroll
    for (int kc = 0; kc < 128; kc += 32) {
        short8 af[4], bf_[4];
#pragma unroll
        for (int im = 0; im < 4; ++im)
            af[im] = *reinterpret_cast<const short8*>(
                &Pb[(mh * 64 + im * 16 + l15) * 136 + kc + quad * 8]);
#pragma unroll
        for (int in = 0; in < 4; ++in)
            bf_[in] = *reinterpret_cast<const short8*>(
                &vT[(nh * 64 + in * 16 + l15) * 136 + kc + quad * 8]);
#pragma unroll
        for (int im = 0; im < 4; ++im)
#pragma unroll
            for (int in = 0; in < 4; ++in)
                acc[im][in] = __builtin_amdgcn_mfma_f32_16x16x32_bf16(
                    af[im], bf_[in], acc[im][in], 0, 0, 0);
    }
    __syncthreads();
#pragma unroll
    for (int im = 0; im < 4; ++im)
#pragma unroll
        for (int in = 0; in < 4; ++in) {
            int col = nh * 64 + in * 16 + l15;
#pragma unroll
            for (int r = 0; r < 4; ++r) {
                int row = mh * 64 + im * 16 + quad * 4 + r;
                Pb[row * 136 + col] = f2bf(acc[im][in][r]);
            }
        }
    __syncthreads();

    float bb[4];
#pragma unroll
    for (int in = 0; in < 4; ++in) bb[in] = bo[nh * 64 + in * 16 + l15];
#pragma unroll
    for (int im = 0; im < 4; ++im)
#pragma unroll
        for (int in = 0; in < 4; ++in)
            acc[im][in] = (floatx4){0.f, 0.f, 0.f, 0.f};
#pragma unroll
    for (int kc = 0; kc < 128; kc += 32) {
        short8 af[4], bf_[4];
#pragma unroll
        for (int im = 0; im < 4; ++im)
            af[im] = *reinterpret_cast<const short8*>(
                &Pb[(mh * 64 + im * 16 + l15) * 136 + kc + quad * 8]);
#pragma unroll
        for (int in = 0; in < 4; ++in)
            bf_[in] = *reinterpret_cast<const short8*>(
                WoB + (nh * 64 + in * 16 + l15) * 128 + kc + quad * 8);
#pragma unroll
        for (int im = 0; im < 4; ++im)
#pragma unroll
            for (int in = 0; in < 4; ++in)
                acc[im][in] = __builtin_amdgcn_mfma_f32_16x16x32_bf16(
                    af[im], bf_[in], acc[im][in], 0, 0, 0);
    }
#pragma unroll
    for (int im = 0; im < 4; ++im)
#pragma unroll
        for (int in = 0; in < 4; ++in) {
            int col = nh * 64 + in * 16 + l15;
#pragma unroll
            for (int r = 0; r < 4; ++r) {
                int row = mh * 64 + im * 16 + quad * 4 + r;
                outp[hb + (size_t)row * 128 + col] = acc[im][in][r] + bb[in];
            }
        }
}

// ---------------------------------------------------------------------------
extern "C" void kernel_launch(void* const* d_in, const int* in_sizes, int n_in,
                              void* d_out, int out_size, void* d_ws, size_t ws_size,
                              hipStream_t stream) {
    const float* x   = (const float*)d_in[0];
    const float* Wq  = (const float*)d_in[2];
    const float* bq  = (const float*)d_in[3];
    const float* Wk  = (const float*)d_in[4];
    const float* bk  = (const float*)d_in[5];
    const float* Wv  = (const float*)d_in[6];
    const float* bv  = (const float*)d_in[7];
    const float* Wo  = (const float*)d_in[8];
    const float* bo  = (const float*)d_in[9];
    const float* Wc1 = (const float*)d_in[10];
    const float* bc1 = (const float*)d_in[11];
    const float* Wc2 = (const float*)d_in[12];
    const float* rel = (const float*)d_in[13];

    char* wsb = (char*)d_ws;
    short* q_bf  = (short*)(wsb);                       // 16 MB
    short* k_bf  = (short*)(wsb + 1ull * 16777216);
    short* v_bf  = (short*)(wsb + 2ull * 16777216);
    short* x_bf  = (short*)(wsb + 3ull * 16777216);
    float* P     = (float*)(wsb + 4ull * 16777216);     // 13.1 MB
    float* W2    = (float*)(wsb + 4ull * 16777216 + 13107200);
    float* cst   = W2 + 6400;
    float* b_eff = cst + 64;
    short* wbf   = (short*)(b_eff + 16);                // 4 x 16384 bf16
    float* outp  = (float*)d_out;

    hipLaunchKernelGGL(k_cvt,   dim3(4128), dim3(256), 0, stream, x, Wq, Wk, Wv, Wo, x_bf, wbf);
    hipLaunchKernelGGL(k_wprep, dim3(50),   dim3(256), 0, stream, Wc1, Wc2, bc1, Wq, bq, W2, cst, b_eff);
    hipLaunchKernelGGL(k_off,   dim3(1024), dim3(256), 0, stream, x, W2, cst, P);
    hipLaunchKernelGGL(k_fused, dim3(512),  dim3(256), 0, stream, P, b_eff, x_bf, wbf,
                       bq, bk, bv, rel, q_bf, k_bf, v_bf);
    hipLaunchKernelGGL(k_attn3, dim3(512),  dim3(256), 0, stream, q_bf, k_bf, v_bf,
                       wbf + 49152, bo, outp);
}